// Round 2
// baseline (482.796 us; speedup 1.0000x reference)
//
#include <hip/hip_runtime.h>
#include <math.h>

#define NEG_SLOPE 0.2f

typedef unsigned int u32;
typedef unsigned short u16;

__device__ __forceinline__ float bf2f(u16 h) {
  union { u32 u; float f; } c; c.u = ((u32)h) << 16; return c.f;
}
__device__ __forceinline__ u16 f2bf(float f) {
  union { float f; u32 u; } c; c.f = f;
  return (u16)((c.u + 0x7FFFu + ((c.u >> 16) & 1u)) >> 16);  // RNE, no NaNs expected
}

// ---------------------------------------------------------------- degree + edge-weight sum
__global__ void k_deg(const int* __restrict__ dst, const float* __restrict__ ew,
                      int* __restrict__ deg, float* __restrict__ sum_ea, int E) {
  int e = blockIdx.x * 256 + threadIdx.x;
  if (e >= E) return;
  int d = dst[e];
  atomicAdd(&deg[d], 1);
  atomicAdd(&sum_ea[d], ew[e]);
}

// ---------------------------------------------------------------- exclusive scan of (deg+1) -> row_ptr, fused mean_ea (in place)
__global__ void k_scan(const int* __restrict__ deg, float* __restrict__ sum_mean,
                       int* __restrict__ row_ptr, int n) {
  __shared__ int sums[1024];
  int t = threadIdx.x;
  int chunk = (n + 1023) >> 10;
  int begin = t * chunk; if (begin > n) begin = n;
  int end = begin + chunk; if (end > n) end = n;
  int s = 0;
  for (int i = begin; i < end; i++) s += deg[i] + 1;
  sums[t] = s;
  __syncthreads();
  for (int off = 1; off < 1024; off <<= 1) {
    int v = (t >= off) ? sums[t - off] : 0;
    __syncthreads();
    sums[t] += v;
    __syncthreads();
  }
  int offset = (t == 0) ? 0 : sums[t - 1];
  for (int i = begin; i < end; i++) {
    int d = deg[i];
    row_ptr[i] = offset;
    offset += d + 1;
    sum_mean[i] = sum_mean[i] / (float)(d > 1 ? d : 1);
  }
  if (t == 1023) row_ptr[n] = offset;
}

// ---------------------------------------------------------------- counting-sort edges (+self loops) into CSR (packed src+weight)
__global__ void k_scatter(const int* __restrict__ src, const int* __restrict__ dst,
                          const float* __restrict__ ew, const float* __restrict__ mean_ea,
                          const int* __restrict__ row_ptr, int* __restrict__ cursor,
                          int2* __restrict__ col_sw, int E, int n) {
  int e = blockIdx.x * 256 + threadIdx.x;
  if (e >= E + n) return;
  int s, d; float wv;
  if (e < E) { s = src[e]; d = dst[e]; wv = ew[e]; }
  else       { s = d = e - E; wv = mean_ea[e - E]; }
  int p = row_ptr[d] + atomicAdd(&cursor[d], 1);
  col_sw[p] = make_int2(s, __float_as_int(wv));
}

// ---------------------------------------------------------------- f32 GEMM (K=128) + bf16 store + fused attn dots
// C = A[nrows x 128] @ B[128 x H*64]; block: 32 rows x 64 cols (one head).
template<int H>
__global__ __launch_bounds__(256) void k_gemm(const float* __restrict__ A,
                                              const float* __restrict__ B,
                                              u16* __restrict__ xs_bf,
                                              const float* __restrict__ att_src,
                                              const float* __restrict__ att_dst,
                                              float* __restrict__ a_src_out,
                                              float* __restrict__ a_dst_out,
                                              int nrows) {
  const int ncols = H * 64;
  __shared__ float Bs[128 * 64];
  int h = blockIdx.y;
  int c0 = h * 64;
  for (int i = threadIdx.x; i < 128 * 16; i += 256) {
    int k = i >> 4, c4 = (i & 15) << 2;
    *(float4*)&Bs[k * 64 + c4] = *(const float4*)&B[(size_t)k * ncols + c0 + c4];
  }
  __syncthreads();
  int rp = threadIdx.x >> 4;          // 0..15 row-pair
  int cq = (threadIdx.x & 15) << 2;   // col quad within 64
  int r0 = blockIdx.x * 32 + rp * 2, r1 = r0 + 1;
  bool v0 = r0 < nrows, v1 = r1 < nrows;
  const float4* A0 = (const float4*)(A + (size_t)(v0 ? r0 : 0) * 128);
  const float4* A1 = (const float4*)(A + (size_t)(v1 ? r1 : 0) * 128);
  float4 acc0 = {0,0,0,0}, acc1 = {0,0,0,0};
  #pragma unroll 8
  for (int k4 = 0; k4 < 32; k4++) {
    float4 a0 = A0[k4], a1 = A1[k4];
    float a0s[4] = {a0.x, a0.y, a0.z, a0.w};
    float a1s[4] = {a1.x, a1.y, a1.z, a1.w};
    #pragma unroll
    for (int kk = 0; kk < 4; kk++) {
      float4 b = *(const float4*)&Bs[(4 * k4 + kk) * 64 + cq];
      acc0.x += a0s[kk] * b.x; acc0.y += a0s[kk] * b.y;
      acc0.z += a0s[kk] * b.z; acc0.w += a0s[kk] * b.w;
      acc1.x += a1s[kk] * b.x; acc1.y += a1s[kk] * b.y;
      acc1.z += a1s[kk] * b.z; acc1.w += a1s[kk] * b.w;
    }
  }
  if (v0) {
    ushort4 o = { f2bf(acc0.x), f2bf(acc0.y), f2bf(acc0.z), f2bf(acc0.w) };
    *(ushort4*)&xs_bf[(size_t)r0 * ncols + c0 + cq] = o;
  }
  if (v1) {
    ushort4 o = { f2bf(acc1.x), f2bf(acc1.y), f2bf(acc1.z), f2bf(acc1.w) };
    *(ushort4*)&xs_bf[(size_t)r1 * ncols + c0 + cq] = o;
  }
  // fused attention coefficients: reduce over the 16 lanes sharing a row pair
  float4 as = *(const float4*)&att_src[c0 + cq];
  float4 ad = *(const float4*)&att_dst[c0 + cq];
  float ps0 = acc0.x*as.x + acc0.y*as.y + acc0.z*as.z + acc0.w*as.w;
  float pd0 = acc0.x*ad.x + acc0.y*ad.y + acc0.z*ad.z + acc0.w*ad.w;
  float ps1 = acc1.x*as.x + acc1.y*as.y + acc1.z*as.z + acc1.w*as.w;
  float pd1 = acc1.x*ad.x + acc1.y*ad.y + acc1.z*ad.z + acc1.w*ad.w;
  #pragma unroll
  for (int off = 8; off; off >>= 1) {
    ps0 += __shfl_xor(ps0, off); pd0 += __shfl_xor(pd0, off);
    ps1 += __shfl_xor(ps1, off); pd1 += __shfl_xor(pd1, off);
  }
  if ((threadIdx.x & 15) == 0) {
    if (v0) { a_src_out[r0 * H + h] = ps0; a_dst_out[r0 * H + h] = pd0; }
    if (v1) { a_src_out[r1 * H + h] = ps1; a_dst_out[r1 * H + h] = pd1; }
  }
}

// ---------------------------------------------------------------- edge-attention scalars: s1[0],s1[1],s2
__global__ void k_scalars(const float* __restrict__ We1, const float* __restrict__ ae1,
                          const float* __restrict__ We2, const float* __restrict__ ae2,
                          float* __restrict__ out) {
  int t = threadIdx.x;
  if (t == 0) { float s = 0; for (int c = 0; c < 64; c++) s += We1[c] * ae1[c]; out[0] = s; }
  if (t == 1) { float s = 0; for (int c = 0; c < 64; c++) s += We1[64 + c] * ae1[64 + c]; out[1] = s; }
  if (t == 2) { float s = 0; for (int c = 0; c < 64; c++) s += We2[c] * ae2[c]; out[2] = s; }
}

// ---------------------------------------------------------------- fused logits + online softmax + aggregate, layer 1 (H=2) + bias + ELU
// One wave per node; lane l owns edge beg+l (+64 chunks); lane l holds features 2l,2l+1.
__global__ __launch_bounds__(256) void k_agg1(const int* __restrict__ row_ptr,
                                              const int2* __restrict__ col_sw,
                                              const float2* __restrict__ a_src,
                                              const float2* __restrict__ a_dst,
                                              const float* __restrict__ scal,
                                              const u16* __restrict__ xs_bf,
                                              const float* __restrict__ b1,
                                              float* __restrict__ h_out, int n) {
  int wid = (blockIdx.x * 256 + threadIdx.x) >> 6;
  int lane = threadIdx.x & 63;
  if (wid >= n) return;
  int beg = row_ptr[wid], end = row_ptr[wid + 1];
  float2 ad = a_dst[wid];
  float sc0 = scal[0], sc1 = scal[1];
  bool hi = lane >= 32;                       // features 2l,2l+1 belong to head (l>=32)
  float m0 = -1e30f, m1 = -1e30f, den0 = 0.f, den1 = 0.f;
  float accx = 0.f, accy = 0.f;
  for (int p0 = beg; p0 < end; p0 += 64) {
    int p = p0 + lane;
    bool act = p < end;
    int2 sw = col_sw[act ? p : beg];
    int s = sw.x;
    float w = __int_as_float(sw.y);
    float2 asv = a_src[s];
    float l0 = asv.x + ad.x + w * sc0;
    float l1 = asv.y + ad.y + w * sc1;
    l0 = l0 > 0.f ? l0 : NEG_SLOPE * l0;
    l1 = l1 > 0.f ? l1 : NEG_SLOPE * l1;
    if (!act) { l0 = -1e30f; l1 = -1e30f; }
    float cm0 = l0, cm1 = l1;
    #pragma unroll
    for (int off = 32; off; off >>= 1) {
      cm0 = fmaxf(cm0, __shfl_xor(cm0, off));
      cm1 = fmaxf(cm1, __shfl_xor(cm1, off));
    }
    float nm0 = fmaxf(m0, cm0), nm1 = fmaxf(m1, cm1);
    float e0 = __expf(l0 - nm0), e1 = __expf(l1 - nm1);   // 0 for inactive lanes
    float cs0 = e0, cs1 = e1;
    #pragma unroll
    for (int off = 32; off; off >>= 1) {
      cs0 += __shfl_xor(cs0, off);
      cs1 += __shfl_xor(cs1, off);
    }
    float r0 = __expf(m0 - nm0), r1 = __expf(m1 - nm1);   // first chunk: exp(-huge)=0
    den0 = den0 * r0 + cs0;
    den1 = den1 * r1 + cs1;
    float rs = hi ? r1 : r0;
    accx *= rs; accy *= rs;
    m0 = nm0; m1 = nm1;
    int cnt = end - p0; if (cnt > 64) cnt = 64;
    for (int j = 0; j < cnt; j++) {
      float a0 = __shfl(e0, j);
      float a1 = __shfl(e1, j);
      int   sj = __shfl(s, j);
      u32 pr = *(const u32*)&xs_bf[(size_t)sj * 128 + 2 * lane];
      float al = hi ? a1 : a0;
      accx += al * bf2f((u16)pr);
      accy += al * bf2f((u16)(pr >> 16));
    }
  }
  float inv = 1.f / ((hi ? den1 : den0) + 1e-16f);
  float o0 = accx * inv + b1[2 * lane];
  float o1 = accy * inv + b1[2 * lane + 1];
  o0 = o0 > 0.f ? o0 : expm1f(o0);   // ELU
  o1 = o1 > 0.f ? o1 : expm1f(o1);
  *(float2*)&h_out[(size_t)wid * 128 + 2 * lane] = make_float2(o0, o1);
}

// ---------------------------------------------------------------- fused logits + online softmax + aggregate, layer 2 (H=1) + bias
__global__ __launch_bounds__(256) void k_agg2(const int* __restrict__ row_ptr,
                                              const int2* __restrict__ col_sw,
                                              const float* __restrict__ a_src,
                                              const float* __restrict__ a_dst,
                                              const float* __restrict__ scal,
                                              const u16* __restrict__ xs_bf,
                                              const float* __restrict__ b2,
                                              float* __restrict__ out, int n) {
  int wid = (blockIdx.x * 256 + threadIdx.x) >> 6;
  int lane = threadIdx.x & 63;
  if (wid >= n) return;
  int beg = row_ptr[wid], end = row_ptr[wid + 1];
  float adv = a_dst[wid];
  float sc = scal[2];
  float m = -1e30f, den = 0.f, acc = 0.f;
  for (int p0 = beg; p0 < end; p0 += 64) {
    int p = p0 + lane;
    bool act = p < end;
    int2 sw = col_sw[act ? p : beg];
    int s = sw.x;
    float w = __int_as_float(sw.y);
    float l = a_src[s] + adv + w * sc;
    l = l > 0.f ? l : NEG_SLOPE * l;
    if (!act) l = -1e30f;
    float cm = l;
    #pragma unroll
    for (int off = 32; off; off >>= 1) cm = fmaxf(cm, __shfl_xor(cm, off));
    float nm = fmaxf(m, cm);
    float e = __expf(l - nm);
    float cs = e;
    #pragma unroll
    for (int off = 32; off; off >>= 1) cs += __shfl_xor(cs, off);
    float r = __expf(m - nm);
    den = den * r + cs;
    acc *= r;
    m = nm;
    int cnt = end - p0; if (cnt > 64) cnt = 64;
    for (int j = 0; j < cnt; j++) {
      float aj = __shfl(e, j);
      int   sj = __shfl(s, j);
      acc += aj * bf2f(xs_bf[(size_t)sj * 64 + lane]);
    }
  }
  out[(size_t)wid * 64 + lane] = acc / (den + 1e-16f) + b2[lane];
}

// ================================================================ launch
extern "C" void kernel_launch(void* const* d_in, const int* in_sizes, int n_in,
                              void* d_out, int out_size, void* d_ws, size_t ws_size,
                              hipStream_t stream) {
  const float* x   = (const float*)d_in[0];
  const int*   ei  = (const int*)d_in[1];
  const float* ew  = (const float*)d_in[2];
  const float* W1  = (const float*)d_in[3];
  const float* as1 = (const float*)d_in[4];
  const float* ad1 = (const float*)d_in[5];
  const float* We1 = (const float*)d_in[6];
  const float* ae1 = (const float*)d_in[7];
  const float* b1  = (const float*)d_in[8];
  const float* W2  = (const float*)d_in[9];
  const float* as2 = (const float*)d_in[10];
  const float* ad2 = (const float*)d_in[11];
  const float* We2 = (const float*)d_in[12];
  const float* ae2 = (const float*)d_in[13];
  const float* b2  = (const float*)d_in[14];

  const int n = in_sizes[0] / 128;
  const int E = in_sizes[1] / 2;
  const int Etot = E + n;

  char* wsb = (char*)d_ws;
  size_t off = 0;
  auto alloc = [&](size_t bytes) -> void* {
    void* p = wsb + off; off += (bytes + 255) & ~(size_t)255; return p;
  };
  int*   deg     = (int*)  alloc((size_t)n * 4);
  float* mean_ea = (float*)alloc((size_t)n * 4);       // sum_ea, then mean in place
  int*   row_ptr = (int*)  alloc((size_t)(n + 1) * 4);
  int*   cursor  = (int*)  alloc((size_t)n * 4);
  int2*  col_sw  = (int2*) alloc((size_t)Etot * 8);
  u16*   xs_bf   = (u16*)  alloc((size_t)n * 128 * 2); // layer1; reused layer2 (n*64)
  float* h1      = (float*)alloc((size_t)n * 128 * 4);
  float* a_src1v = (float*)alloc((size_t)n * 2 * 4);
  float* a_dst1v = (float*)alloc((size_t)n * 2 * 4);
  float* a_src2v = (float*)alloc((size_t)n * 4);
  float* a_dst2v = (float*)alloc((size_t)n * 4);
  float* scal    = (float*)alloc(64);
  if (off > ws_size) return;

  hipMemsetAsync(deg, 0, (size_t)n * 4, stream);
  hipMemsetAsync(mean_ea, 0, (size_t)n * 4, stream);
  hipMemsetAsync(cursor, 0, (size_t)n * 4, stream);

  dim3 B(256);
  k_deg<<<dim3((E + 255) / 256), B, 0, stream>>>(ei + E, ew, deg, mean_ea, E);
  k_scan<<<1, 1024, 0, stream>>>(deg, mean_ea, row_ptr, n);
  k_scatter<<<dim3((Etot + 255) / 256), B, 0, stream>>>(ei, ei + E, ew, mean_ea, row_ptr,
                                                        cursor, col_sw, E, n);
  k_scalars<<<1, 64, 0, stream>>>(We1, ae1, We2, ae2, scal);
  // layer 1
  k_gemm<2><<<dim3((n + 31) / 32, 2), B, 0, stream>>>(x, W1, xs_bf, as1, ad1,
                                                      a_src1v, a_dst1v, n);
  k_agg1<<<dim3((n * 64 + 255) / 256), B, 0, stream>>>(row_ptr, col_sw,
                                                       (const float2*)a_src1v,
                                                       (const float2*)a_dst1v,
                                                       scal, xs_bf, b1, h1, n);
  // layer 2
  k_gemm<1><<<dim3((n + 31) / 32, 1), B, 0, stream>>>(h1, W2, xs_bf, as2, ad2,
                                                      a_src2v, a_dst2v, n);
  k_agg2<<<dim3((n * 64 + 255) / 256), B, 0, stream>>>(row_ptr, col_sw, a_src2v, a_dst2v,
                                                       scal, xs_bf, b2, (float*)d_out, n);
}

// Round 3
// 328.720 us; speedup vs baseline: 1.4687x; 1.4687x over previous
//
#include <hip/hip_runtime.h>
#include <math.h>

#define NEG_SLOPE 0.2f

typedef unsigned int u32;
typedef unsigned short u16;

__device__ __forceinline__ float bf2f(u16 h) {
  union { u32 u; float f; } c; c.u = ((u32)h) << 16; return c.f;
}
__device__ __forceinline__ u16 f2bf(float f) {
  union { float f; u32 u; } c; c.f = f;
  return (u16)((c.u + 0x7FFFu + ((c.u >> 16) & 1u)) >> 16);  // RNE, no NaNs expected
}

// ---------------------------------------------------------------- degree + edge-weight sum
__global__ void k_deg(const int* __restrict__ dst, const float* __restrict__ ew,
                      int* __restrict__ deg, float* __restrict__ sum_ea, int E) {
  int e = blockIdx.x * 256 + threadIdx.x;
  if (e >= E) return;
  int d = dst[e];
  atomicAdd(&deg[d], 1);
  atomicAdd(&sum_ea[d], ew[e]);
}

// ---------------------------------------------------------------- hierarchical scan of (deg+1) -> row_ptr
// phase 1: per-block partial sums
__global__ __launch_bounds__(256) void k_part(const int* __restrict__ deg,
                                              int* __restrict__ part, int n) {
  int i = blockIdx.x * 256 + threadIdx.x;
  int v = (i < n) ? deg[i] + 1 : 0;
  #pragma unroll
  for (int off = 32; off; off >>= 1) v += __shfl_xor(v, off);
  __shared__ int ws[4];
  if ((threadIdx.x & 63) == 0) ws[threadIdx.x >> 6] = v;
  __syncthreads();
  if (threadIdx.x == 0) part[blockIdx.x] = ws[0] + ws[1] + ws[2] + ws[3];
}

// phase 2: one block scans the partials (exclusive, in place)
__global__ __launch_bounds__(256) void k_scanpart(int* __restrict__ part, int nb) {
  __shared__ int wsum[4];
  int carry = 0;
  for (int base = 0; base < nb; base += 256) {
    int idx = base + threadIdx.x;
    int orig = (idx < nb) ? part[idx] : 0;
    int v = orig;
    #pragma unroll
    for (int off = 1; off < 64; off <<= 1) {
      int u = __shfl_up(v, off);
      if ((threadIdx.x & 63) >= off) v += u;
    }
    if ((threadIdx.x & 63) == 63) wsum[threadIdx.x >> 6] = v;
    __syncthreads();
    int w = threadIdx.x >> 6;
    int add = 0;
    if (w > 0) add += wsum[0];
    if (w > 1) add += wsum[1];
    if (w > 2) add += wsum[2];
    int excl = v - orig + add + carry;
    if (idx < nb) part[idx] = excl;
    int total = wsum[0] + wsum[1] + wsum[2] + wsum[3];
    __syncthreads();
    carry += total;
  }
}

// phase 3: per-block exclusive scan + block offset -> row_ptr; fused mean_ea
__global__ __launch_bounds__(256) void k_rowptr(const int* __restrict__ deg,
                                                const int* __restrict__ part_off,
                                                float* __restrict__ sum_mean,
                                                int* __restrict__ row_ptr, int n) {
  int i = blockIdx.x * 256 + threadIdx.x;
  int d = (i < n) ? deg[i] : 0;
  int orig = (i < n) ? d + 1 : 0;
  int v = orig;
  #pragma unroll
  for (int off = 1; off < 64; off <<= 1) {
    int u = __shfl_up(v, off);
    if ((threadIdx.x & 63) >= off) v += u;
  }
  __shared__ int wsum[4];
  if ((threadIdx.x & 63) == 63) wsum[threadIdx.x >> 6] = v;
  __syncthreads();
  int w = threadIdx.x >> 6;
  int add = 0;
  if (w > 0) add += wsum[0];
  if (w > 1) add += wsum[1];
  if (w > 2) add += wsum[2];
  if (i < n) {
    int excl = v - orig + add + part_off[blockIdx.x];
    row_ptr[i] = excl;
    sum_mean[i] = sum_mean[i] / (float)(d > 1 ? d : 1);
    if (i == n - 1) row_ptr[n] = excl + orig;
  }
}

// ---------------------------------------------------------------- counting-sort edges (+self loops) into CSR (packed src+weight)
__global__ void k_scatter(const int* __restrict__ src, const int* __restrict__ dst,
                          const float* __restrict__ ew, const float* __restrict__ mean_ea,
                          const int* __restrict__ row_ptr, int* __restrict__ cursor,
                          int2* __restrict__ col_sw, int E, int n) {
  int e = blockIdx.x * 256 + threadIdx.x;
  if (e >= E + n) return;
  int s, d; float wv;
  if (e < E) { s = src[e]; d = dst[e]; wv = ew[e]; }
  else       { s = d = e - E; wv = mean_ea[e - E]; }
  int p = row_ptr[d] + atomicAdd(&cursor[d], 1);
  col_sw[p] = make_int2(s, __float_as_int(wv));
}

// ---------------------------------------------------------------- f32 GEMM (K=128) + bf16 store + fused attn dots
template<int H>
__global__ __launch_bounds__(256) void k_gemm(const float* __restrict__ A,
                                              const float* __restrict__ B,
                                              u16* __restrict__ xs_bf,
                                              const float* __restrict__ att_src,
                                              const float* __restrict__ att_dst,
                                              float* __restrict__ a_src_out,
                                              float* __restrict__ a_dst_out,
                                              int nrows) {
  const int ncols = H * 64;
  __shared__ float Bs[128 * 64];
  int h = blockIdx.y;
  int c0 = h * 64;
  for (int i = threadIdx.x; i < 128 * 16; i += 256) {
    int k = i >> 4, c4 = (i & 15) << 2;
    *(float4*)&Bs[k * 64 + c4] = *(const float4*)&B[(size_t)k * ncols + c0 + c4];
  }
  __syncthreads();
  int rp = threadIdx.x >> 4;          // 0..15 row-pair
  int cq = (threadIdx.x & 15) << 2;   // col quad within 64
  int r0 = blockIdx.x * 32 + rp * 2, r1 = r0 + 1;
  bool v0 = r0 < nrows, v1 = r1 < nrows;
  const float4* A0 = (const float4*)(A + (size_t)(v0 ? r0 : 0) * 128);
  const float4* A1 = (const float4*)(A + (size_t)(v1 ? r1 : 0) * 128);
  float4 acc0 = {0,0,0,0}, acc1 = {0,0,0,0};
  #pragma unroll 8
  for (int k4 = 0; k4 < 32; k4++) {
    float4 a0 = A0[k4], a1 = A1[k4];
    float a0s[4] = {a0.x, a0.y, a0.z, a0.w};
    float a1s[4] = {a1.x, a1.y, a1.z, a1.w};
    #pragma unroll
    for (int kk = 0; kk < 4; kk++) {
      float4 b = *(const float4*)&Bs[(4 * k4 + kk) * 64 + cq];
      acc0.x += a0s[kk] * b.x; acc0.y += a0s[kk] * b.y;
      acc0.z += a0s[kk] * b.z; acc0.w += a0s[kk] * b.w;
      acc1.x += a1s[kk] * b.x; acc1.y += a1s[kk] * b.y;
      acc1.z += a1s[kk] * b.z; acc1.w += a1s[kk] * b.w;
    }
  }
  if (v0) {
    ushort4 o = { f2bf(acc0.x), f2bf(acc0.y), f2bf(acc0.z), f2bf(acc0.w) };
    *(ushort4*)&xs_bf[(size_t)r0 * ncols + c0 + cq] = o;
  }
  if (v1) {
    ushort4 o = { f2bf(acc1.x), f2bf(acc1.y), f2bf(acc1.z), f2bf(acc1.w) };
    *(ushort4*)&xs_bf[(size_t)r1 * ncols + c0 + cq] = o;
  }
  float4 as = *(const float4*)&att_src[c0 + cq];
  float4 ad = *(const float4*)&att_dst[c0 + cq];
  float ps0 = acc0.x*as.x + acc0.y*as.y + acc0.z*as.z + acc0.w*as.w;
  float pd0 = acc0.x*ad.x + acc0.y*ad.y + acc0.z*ad.z + acc0.w*ad.w;
  float ps1 = acc1.x*as.x + acc1.y*as.y + acc1.z*as.z + acc1.w*as.w;
  float pd1 = acc1.x*ad.x + acc1.y*ad.y + acc1.z*ad.z + acc1.w*ad.w;
  #pragma unroll
  for (int off = 8; off; off >>= 1) {
    ps0 += __shfl_xor(ps0, off); pd0 += __shfl_xor(pd0, off);
    ps1 += __shfl_xor(ps1, off); pd1 += __shfl_xor(pd1, off);
  }
  if ((threadIdx.x & 15) == 0) {
    if (v0) { a_src_out[r0 * H + h] = ps0; a_dst_out[r0 * H + h] = pd0; }
    if (v1) { a_src_out[r1 * H + h] = ps1; a_dst_out[r1 * H + h] = pd1; }
  }
}

// ---------------------------------------------------------------- edge-attention scalars: s1[0],s1[1],s2
__global__ void k_scalars(const float* __restrict__ We1, const float* __restrict__ ae1,
                          const float* __restrict__ We2, const float* __restrict__ ae2,
                          float* __restrict__ out) {
  int t = threadIdx.x;
  if (t == 0) { float s = 0; for (int c = 0; c < 64; c++) s += We1[c] * ae1[c]; out[0] = s; }
  if (t == 1) { float s = 0; for (int c = 0; c < 64; c++) s += We1[64 + c] * ae1[64 + c]; out[1] = s; }
  if (t == 2) { float s = 0; for (int c = 0; c < 64; c++) s += We2[c] * ae2[c]; out[2] = s; }
}

// ---------------------------------------------------------------- fused logits + online softmax + aggregate, layer 1 (H=2) + bias + ELU
__global__ __launch_bounds__(256) void k_agg1(const int* __restrict__ row_ptr,
                                              const int2* __restrict__ col_sw,
                                              const float2* __restrict__ a_src,
                                              const float2* __restrict__ a_dst,
                                              const float* __restrict__ scal,
                                              const u16* __restrict__ xs_bf,
                                              const float* __restrict__ b1,
                                              float* __restrict__ h_out, int n) {
  int wid = (blockIdx.x * 256 + threadIdx.x) >> 6;
  int lane = threadIdx.x & 63;
  if (wid >= n) return;
  int beg = row_ptr[wid], end = row_ptr[wid + 1];
  float2 ad = a_dst[wid];
  float sc0 = scal[0], sc1 = scal[1];
  bool hi = lane >= 32;
  float m0 = -1e30f, m1 = -1e30f, den0 = 0.f, den1 = 0.f;
  float accx = 0.f, accy = 0.f;
  for (int p0 = beg; p0 < end; p0 += 64) {
    int p = p0 + lane;
    bool act = p < end;
    int2 sw = col_sw[act ? p : beg];
    int s = sw.x;
    float w = __int_as_float(sw.y);
    float2 asv = a_src[s];
    float l0 = asv.x + ad.x + w * sc0;
    float l1 = asv.y + ad.y + w * sc1;
    l0 = l0 > 0.f ? l0 : NEG_SLOPE * l0;
    l1 = l1 > 0.f ? l1 : NEG_SLOPE * l1;
    if (!act) { l0 = -1e30f; l1 = -1e30f; }
    float cm0 = l0, cm1 = l1;
    #pragma unroll
    for (int off = 32; off; off >>= 1) {
      cm0 = fmaxf(cm0, __shfl_xor(cm0, off));
      cm1 = fmaxf(cm1, __shfl_xor(cm1, off));
    }
    float nm0 = fmaxf(m0, cm0), nm1 = fmaxf(m1, cm1);
    float e0 = __expf(l0 - nm0), e1 = __expf(l1 - nm1);
    float cs0 = e0, cs1 = e1;
    #pragma unroll
    for (int off = 32; off; off >>= 1) {
      cs0 += __shfl_xor(cs0, off);
      cs1 += __shfl_xor(cs1, off);
    }
    float r0 = __expf(m0 - nm0), r1 = __expf(m1 - nm1);
    den0 = den0 * r0 + cs0;
    den1 = den1 * r1 + cs1;
    float rs = hi ? r1 : r0;
    accx *= rs; accy *= rs;
    m0 = nm0; m1 = nm1;
    int cnt = end - p0; if (cnt > 64) cnt = 64;
    for (int j = 0; j < cnt; j++) {
      float a0 = __shfl(e0, j);
      float a1 = __shfl(e1, j);
      int   sj = __shfl(s, j);
      u32 pr = *(const u32*)&xs_bf[(size_t)sj * 128 + 2 * lane];
      float al = hi ? a1 : a0;
      accx += al * bf2f((u16)pr);
      accy += al * bf2f((u16)(pr >> 16));
    }
  }
  float inv = 1.f / ((hi ? den1 : den0) + 1e-16f);
  float o0 = accx * inv + b1[2 * lane];
  float o1 = accy * inv + b1[2 * lane + 1];
  o0 = o0 > 0.f ? o0 : expm1f(o0);   // ELU
  o1 = o1 > 0.f ? o1 : expm1f(o1);
  *(float2*)&h_out[(size_t)wid * 128 + 2 * lane] = make_float2(o0, o1);
}

// ---------------------------------------------------------------- fused logits + online softmax + aggregate, layer 2 (H=1) + bias
__global__ __launch_bounds__(256) void k_agg2(const int* __restrict__ row_ptr,
                                              const int2* __restrict__ col_sw,
                                              const float* __restrict__ a_src,
                                              const float* __restrict__ a_dst,
                                              const float* __restrict__ scal,
                                              const u16* __restrict__ xs_bf,
                                              const float* __restrict__ b2,
                                              float* __restrict__ out, int n) {
  int wid = (blockIdx.x * 256 + threadIdx.x) >> 6;
  int lane = threadIdx.x & 63;
  if (wid >= n) return;
  int beg = row_ptr[wid], end = row_ptr[wid + 1];
  float adv = a_dst[wid];
  float sc = scal[2];
  float m = -1e30f, den = 0.f, acc = 0.f;
  for (int p0 = beg; p0 < end; p0 += 64) {
    int p = p0 + lane;
    bool act = p < end;
    int2 sw = col_sw[act ? p : beg];
    int s = sw.x;
    float w = __int_as_float(sw.y);
    float l = a_src[s] + adv + w * sc;
    l = l > 0.f ? l : NEG_SLOPE * l;
    if (!act) l = -1e30f;
    float cm = l;
    #pragma unroll
    for (int off = 32; off; off >>= 1) cm = fmaxf(cm, __shfl_xor(cm, off));
    float nm = fmaxf(m, cm);
    float e = __expf(l - nm);
    float cs = e;
    #pragma unroll
    for (int off = 32; off; off >>= 1) cs += __shfl_xor(cs, off);
    float r = __expf(m - nm);
    den = den * r + cs;
    acc *= r;
    m = nm;
    int cnt = end - p0; if (cnt > 64) cnt = 64;
    for (int j = 0; j < cnt; j++) {
      float aj = __shfl(e, j);
      int   sj = __shfl(s, j);
      acc += aj * bf2f(xs_bf[(size_t)sj * 64 + lane]);
    }
  }
  out[(size_t)wid * 64 + lane] = acc / (den + 1e-16f) + b2[lane];
}

// ================================================================ launch
extern "C" void kernel_launch(void* const* d_in, const int* in_sizes, int n_in,
                              void* d_out, int out_size, void* d_ws, size_t ws_size,
                              hipStream_t stream) {
  const float* x   = (const float*)d_in[0];
  const int*   ei  = (const int*)d_in[1];
  const float* ew  = (const float*)d_in[2];
  const float* W1  = (const float*)d_in[3];
  const float* as1 = (const float*)d_in[4];
  const float* ad1 = (const float*)d_in[5];
  const float* We1 = (const float*)d_in[6];
  const float* ae1 = (const float*)d_in[7];
  const float* b1  = (const float*)d_in[8];
  const float* W2  = (const float*)d_in[9];
  const float* as2 = (const float*)d_in[10];
  const float* ad2 = (const float*)d_in[11];
  const float* We2 = (const float*)d_in[12];
  const float* ae2 = (const float*)d_in[13];
  const float* b2  = (const float*)d_in[14];

  const int n = in_sizes[0] / 128;
  const int E = in_sizes[1] / 2;
  const int Etot = E + n;
  const int nb = (n + 255) / 256;

  char* wsb = (char*)d_ws;
  size_t off = 0;
  auto alloc = [&](size_t bytes) -> void* {
    void* p = wsb + off; off += (bytes + 255) & ~(size_t)255; return p;
  };
  int*   deg     = (int*)  alloc((size_t)n * 4);
  float* mean_ea = (float*)alloc((size_t)n * 4);       // sum_ea, then mean in place
  int*   row_ptr = (int*)  alloc((size_t)(n + 1) * 4);
  int*   cursor  = (int*)  alloc((size_t)n * 4);
  int*   part    = (int*)  alloc((size_t)nb * 4);
  int2*  col_sw  = (int2*) alloc((size_t)Etot * 8);
  u16*   xs_bf   = (u16*)  alloc((size_t)n * 128 * 2); // layer1; reused layer2 (n*64)
  float* h1      = (float*)alloc((size_t)n * 128 * 4);
  float* a_src1v = (float*)alloc((size_t)n * 2 * 4);
  float* a_dst1v = (float*)alloc((size_t)n * 2 * 4);
  float* a_src2v = (float*)alloc((size_t)n * 4);
  float* a_dst2v = (float*)alloc((size_t)n * 4);
  float* scal    = (float*)alloc(64);
  if (off > ws_size) return;

  hipMemsetAsync(deg, 0, (size_t)n * 4, stream);
  hipMemsetAsync(mean_ea, 0, (size_t)n * 4, stream);
  hipMemsetAsync(cursor, 0, (size_t)n * 4, stream);

  dim3 B(256);
  k_deg<<<dim3((E + 255) / 256), B, 0, stream>>>(ei + E, ew, deg, mean_ea, E);
  k_part<<<dim3(nb), B, 0, stream>>>(deg, part, n);
  k_scanpart<<<1, B, 0, stream>>>(part, nb);
  k_rowptr<<<dim3(nb), B, 0, stream>>>(deg, part, mean_ea, row_ptr, n);
  k_scatter<<<dim3((Etot + 255) / 256), B, 0, stream>>>(ei, ei + E, ew, mean_ea, row_ptr,
                                                        cursor, col_sw, E, n);
  k_scalars<<<1, 64, 0, stream>>>(We1, ae1, We2, ae2, scal);
  // layer 1
  k_gemm<2><<<dim3((n + 31) / 32, 2), B, 0, stream>>>(x, W1, xs_bf, as1, ad1,
                                                      a_src1v, a_dst1v, n);
  k_agg1<<<dim3((n * 64 + 255) / 256), B, 0, stream>>>(row_ptr, col_sw,
                                                       (const float2*)a_src1v,
                                                       (const float2*)a_dst1v,
                                                       scal, xs_bf, b1, h1, n);
  // layer 2
  k_gemm<1><<<dim3((n + 31) / 32, 1), B, 0, stream>>>(h1, W2, xs_bf, as2, ad2,
                                                      a_src2v, a_dst2v, n);
  k_agg2<<<dim3((n * 64 + 255) / 256), B, 0, stream>>>(row_ptr, col_sw, a_src2v, a_dst2v,
                                                       scal, xs_bf, b2, (float*)d_out, n);
}

// Round 4
// 294.931 us; speedup vs baseline: 1.6370x; 1.1146x over previous
//
#include <hip/hip_runtime.h>
#include <math.h>

#define NEG_SLOPE 0.2f

typedef unsigned int u32;
typedef unsigned short u16;
typedef unsigned long long u64;

__device__ __forceinline__ float bf2f(u16 h) {
  union { u32 u; float f; } c; c.u = ((u32)h) << 16; return c.f;
}
__device__ __forceinline__ u16 f2bf(float f) {
  union { float f; u32 u; } c; c.f = f;
  return (u16)((c.u + 0x7FFFu + ((c.u >> 16) & 1u)) >> 16);  // RNE, no NaNs expected
}

// ---------------------------------------------------------------- degree + edge-weight sum, one packed u64 atomic per edge
// packed[d] = (deg << 32) | round(sum_w * 2^20)   (w in [0,1), deg <= ~64 -> low sum < 2^27, no carry into deg)
__global__ void k_deg(const int* __restrict__ dst, const float* __restrict__ ew,
                      u64* __restrict__ packed, int E) {
  int e = blockIdx.x * 256 + threadIdx.x;
  if (e >= E) return;
  u32 fix = __float2uint_rn(ew[e] * 1048576.0f);
  atomicAdd(&packed[dst[e]], (1ULL << 32) | (u64)fix);
}

// ---------------------------------------------------------------- hierarchical scan of (deg+1) -> row_ptr
// phase 1: per-block partial sums
__global__ __launch_bounds__(256) void k_part(const u64* __restrict__ packed,
                                              int* __restrict__ part, int n) {
  int i = blockIdx.x * 256 + threadIdx.x;
  int v = (i < n) ? (int)(packed[i] >> 32) + 1 : 0;
  #pragma unroll
  for (int off = 32; off; off >>= 1) v += __shfl_xor(v, off);
  __shared__ int ws[4];
  if ((threadIdx.x & 63) == 0) ws[threadIdx.x >> 6] = v;
  __syncthreads();
  if (threadIdx.x == 0) part[blockIdx.x] = ws[0] + ws[1] + ws[2] + ws[3];
}

// phase 2: one block scans the partials (exclusive, in place)
__global__ __launch_bounds__(256) void k_scanpart(int* __restrict__ part, int nb) {
  __shared__ int wsum[4];
  int carry = 0;
  for (int base = 0; base < nb; base += 256) {
    int idx = base + threadIdx.x;
    int orig = (idx < nb) ? part[idx] : 0;
    int v = orig;
    #pragma unroll
    for (int off = 1; off < 64; off <<= 1) {
      int u = __shfl_up(v, off);
      if ((threadIdx.x & 63) >= off) v += u;
    }
    if ((threadIdx.x & 63) == 63) wsum[threadIdx.x >> 6] = v;
    __syncthreads();
    int w = threadIdx.x >> 6;
    int add = 0;
    if (w > 0) add += wsum[0];
    if (w > 1) add += wsum[1];
    if (w > 2) add += wsum[2];
    int excl = v - orig + add + carry;
    if (idx < nb) part[idx] = excl;
    int total = wsum[0] + wsum[1] + wsum[2] + wsum[3];
    __syncthreads();
    carry += total;
  }
}

// phase 3: per-block exclusive scan + block offset -> row_ptr; emits the self-loop entry (slot 0)
__global__ __launch_bounds__(256) void k_rowptr(const u64* __restrict__ packed,
                                                const int* __restrict__ part_off,
                                                int* __restrict__ row_ptr,
                                                int2* __restrict__ col_sw, int n) {
  int i = blockIdx.x * 256 + threadIdx.x;
  u64 pk = (i < n) ? packed[i] : 0ULL;
  int d = (int)(pk >> 32);
  int orig = (i < n) ? d + 1 : 0;
  int v = orig;
  #pragma unroll
  for (int off = 1; off < 64; off <<= 1) {
    int u = __shfl_up(v, off);
    if ((threadIdx.x & 63) >= off) v += u;
  }
  __shared__ int wsum[4];
  if ((threadIdx.x & 63) == 63) wsum[threadIdx.x >> 6] = v;
  __syncthreads();
  int w = threadIdx.x >> 6;
  int add = 0;
  if (w > 0) add += wsum[0];
  if (w > 1) add += wsum[1];
  if (w > 2) add += wsum[2];
  if (i < n) {
    int excl = v - orig + add + part_off[blockIdx.x];
    row_ptr[i] = excl;
    float mean = ((float)(u32)pk * (1.0f / 1048576.0f)) / (float)(d > 1 ? d : 1);
    col_sw[excl] = make_int2(i, __float_as_int(mean));   // self-loop at slot 0
    if (i == n - 1) row_ptr[n] = excl + orig;
  }
}

// ---------------------------------------------------------------- counting-sort real edges into CSR slots 1..deg
__global__ void k_scatter(const int* __restrict__ src, const int* __restrict__ dst,
                          const float* __restrict__ ew,
                          const int* __restrict__ row_ptr, int* __restrict__ cursor,
                          int2* __restrict__ col_sw, int E) {
  int e = blockIdx.x * 256 + threadIdx.x;
  if (e >= E) return;
  int d = dst[e];
  int p = row_ptr[d] + 1 + atomicAdd(&cursor[d], 1);
  col_sw[p] = make_int2(src[e], __float_as_int(ew[e]));
}

// ---------------------------------------------------------------- f32 GEMM (K=128) + bf16 store + fused attn dots
template<int H>
__global__ __launch_bounds__(256) void k_gemm(const float* __restrict__ A,
                                              const float* __restrict__ B,
                                              u16* __restrict__ xs_bf,
                                              const float* __restrict__ att_src,
                                              const float* __restrict__ att_dst,
                                              float* __restrict__ a_src_out,
                                              float* __restrict__ a_dst_out,
                                              int nrows) {
  const int ncols = H * 64;
  __shared__ float Bs[128 * 64];
  int h = blockIdx.y;
  int c0 = h * 64;
  for (int i = threadIdx.x; i < 128 * 16; i += 256) {
    int k = i >> 4, c4 = (i & 15) << 2;
    *(float4*)&Bs[k * 64 + c4] = *(const float4*)&B[(size_t)k * ncols + c0 + c4];
  }
  __syncthreads();
  int rp = threadIdx.x >> 4;          // 0..15 row-pair
  int cq = (threadIdx.x & 15) << 2;   // col quad within 64
  int r0 = blockIdx.x * 32 + rp * 2, r1 = r0 + 1;
  bool v0 = r0 < nrows, v1 = r1 < nrows;
  const float4* A0 = (const float4*)(A + (size_t)(v0 ? r0 : 0) * 128);
  const float4* A1 = (const float4*)(A + (size_t)(v1 ? r1 : 0) * 128);
  float4 acc0 = {0,0,0,0}, acc1 = {0,0,0,0};
  #pragma unroll 8
  for (int k4 = 0; k4 < 32; k4++) {
    float4 a0 = A0[k4], a1 = A1[k4];
    float a0s[4] = {a0.x, a0.y, a0.z, a0.w};
    float a1s[4] = {a1.x, a1.y, a1.z, a1.w};
    #pragma unroll
    for (int kk = 0; kk < 4; kk++) {
      float4 b = *(const float4*)&Bs[(4 * k4 + kk) * 64 + cq];
      acc0.x += a0s[kk] * b.x; acc0.y += a0s[kk] * b.y;
      acc0.z += a0s[kk] * b.z; acc0.w += a0s[kk] * b.w;
      acc1.x += a1s[kk] * b.x; acc1.y += a1s[kk] * b.y;
      acc1.z += a1s[kk] * b.z; acc1.w += a1s[kk] * b.w;
    }
  }
  if (v0) {
    ushort4 o = { f2bf(acc0.x), f2bf(acc0.y), f2bf(acc0.z), f2bf(acc0.w) };
    *(ushort4*)&xs_bf[(size_t)r0 * ncols + c0 + cq] = o;
  }
  if (v1) {
    ushort4 o = { f2bf(acc1.x), f2bf(acc1.y), f2bf(acc1.z), f2bf(acc1.w) };
    *(ushort4*)&xs_bf[(size_t)r1 * ncols + c0 + cq] = o;
  }
  float4 as = *(const float4*)&att_src[c0 + cq];
  float4 ad = *(const float4*)&att_dst[c0 + cq];
  float ps0 = acc0.x*as.x + acc0.y*as.y + acc0.z*as.z + acc0.w*as.w;
  float pd0 = acc0.x*ad.x + acc0.y*ad.y + acc0.z*ad.z + acc0.w*ad.w;
  float ps1 = acc1.x*as.x + acc1.y*as.y + acc1.z*as.z + acc1.w*as.w;
  float pd1 = acc1.x*ad.x + acc1.y*ad.y + acc1.z*ad.z + acc1.w*ad.w;
  #pragma unroll
  for (int off = 8; off; off >>= 1) {
    ps0 += __shfl_xor(ps0, off); pd0 += __shfl_xor(pd0, off);
    ps1 += __shfl_xor(ps1, off); pd1 += __shfl_xor(pd1, off);
  }
  if ((threadIdx.x & 15) == 0) {
    if (v0) { a_src_out[r0 * H + h] = ps0; a_dst_out[r0 * H + h] = pd0; }
    if (v1) { a_src_out[r1 * H + h] = ps1; a_dst_out[r1 * H + h] = pd1; }
  }
}

// ---------------------------------------------------------------- edge-attention scalars: s1[0],s1[1],s2
__global__ void k_scalars(const float* __restrict__ We1, const float* __restrict__ ae1,
                          const float* __restrict__ We2, const float* __restrict__ ae2,
                          float* __restrict__ out) {
  int t = threadIdx.x;
  if (t == 0) { float s = 0; for (int c = 0; c < 64; c++) s += We1[c] * ae1[c]; out[0] = s; }
  if (t == 1) { float s = 0; for (int c = 0; c < 64; c++) s += We1[64 + c] * ae1[64 + c]; out[1] = s; }
  if (t == 2) { float s = 0; for (int c = 0; c < 64; c++) s += We2[c] * ae2[c]; out[2] = s; }
}

// ---------------------------------------------------------------- fused logits + online softmax + aggregate, layer 1 (H=2) + bias + ELU
__global__ __launch_bounds__(256) void k_agg1(const int* __restrict__ row_ptr,
                                              const int2* __restrict__ col_sw,
                                              const float2* __restrict__ a_src,
                                              const float2* __restrict__ a_dst,
                                              const float* __restrict__ scal,
                                              const u16* __restrict__ xs_bf,
                                              const float* __restrict__ b1,
                                              float* __restrict__ h_out, int n) {
  int wid = (blockIdx.x * 256 + threadIdx.x) >> 6;
  int lane = threadIdx.x & 63;
  if (wid >= n) return;
  int beg = row_ptr[wid], end = row_ptr[wid + 1];
  float2 ad = a_dst[wid];
  float sc0 = scal[0], sc1 = scal[1];
  bool hi = lane >= 32;
  float m0 = -1e30f, m1 = -1e30f, den0 = 0.f, den1 = 0.f;
  float accx = 0.f, accy = 0.f;
  for (int p0 = beg; p0 < end; p0 += 64) {
    int p = p0 + lane;
    bool act = p < end;
    int2 sw = col_sw[act ? p : beg];
    int s = sw.x;
    float w = __int_as_float(sw.y);
    float2 asv = a_src[s];
    float l0 = asv.x + ad.x + w * sc0;
    float l1 = asv.y + ad.y + w * sc1;
    l0 = l0 > 0.f ? l0 : NEG_SLOPE * l0;
    l1 = l1 > 0.f ? l1 : NEG_SLOPE * l1;
    if (!act) { l0 = -1e30f; l1 = -1e30f; }
    float cm0 = l0, cm1 = l1;
    #pragma unroll
    for (int off = 32; off; off >>= 1) {
      cm0 = fmaxf(cm0, __shfl_xor(cm0, off));
      cm1 = fmaxf(cm1, __shfl_xor(cm1, off));
    }
    float nm0 = fmaxf(m0, cm0), nm1 = fmaxf(m1, cm1);
    float e0 = __expf(l0 - nm0), e1 = __expf(l1 - nm1);
    float cs0 = e0, cs1 = e1;
    #pragma unroll
    for (int off = 32; off; off >>= 1) {
      cs0 += __shfl_xor(cs0, off);
      cs1 += __shfl_xor(cs1, off);
    }
    float r0 = __expf(m0 - nm0), r1 = __expf(m1 - nm1);
    den0 = den0 * r0 + cs0;
    den1 = den1 * r1 + cs1;
    float rs = hi ? r1 : r0;
    accx *= rs; accy *= rs;
    m0 = nm0; m1 = nm1;
    int cnt = end - p0; if (cnt > 64) cnt = 64;
    for (int j = 0; j < cnt; j++) {
      float a0 = __shfl(e0, j);
      float a1 = __shfl(e1, j);
      int   sj = __shfl(s, j);
      u32 pr = *(const u32*)&xs_bf[(size_t)sj * 128 + 2 * lane];
      float al = hi ? a1 : a0;
      accx += al * bf2f((u16)pr);
      accy += al * bf2f((u16)(pr >> 16));
    }
  }
  float inv = 1.f / ((hi ? den1 : den0) + 1e-16f);
  float o0 = accx * inv + b1[2 * lane];
  float o1 = accy * inv + b1[2 * lane + 1];
  o0 = o0 > 0.f ? o0 : expm1f(o0);   // ELU
  o1 = o1 > 0.f ? o1 : expm1f(o1);
  *(float2*)&h_out[(size_t)wid * 128 + 2 * lane] = make_float2(o0, o1);
}

// ---------------------------------------------------------------- fused logits + online softmax + aggregate, layer 2 (H=1) + bias
__global__ __launch_bounds__(256) void k_agg2(const int* __restrict__ row_ptr,
                                              const int2* __restrict__ col_sw,
                                              const float* __restrict__ a_src,
                                              const float* __restrict__ a_dst,
                                              const float* __restrict__ scal,
                                              const u16* __restrict__ xs_bf,
                                              const float* __restrict__ b2,
                                              float* __restrict__ out, int n) {
  int wid = (blockIdx.x * 256 + threadIdx.x) >> 6;
  int lane = threadIdx.x & 63;
  if (wid >= n) return;
  int beg = row_ptr[wid], end = row_ptr[wid + 1];
  float adv = a_dst[wid];
  float sc = scal[2];
  float m = -1e30f, den = 0.f, acc = 0.f;
  for (int p0 = beg; p0 < end; p0 += 64) {
    int p = p0 + lane;
    bool act = p < end;
    int2 sw = col_sw[act ? p : beg];
    int s = sw.x;
    float w = __int_as_float(sw.y);
    float l = a_src[s] + adv + w * sc;
    l = l > 0.f ? l : NEG_SLOPE * l;
    if (!act) l = -1e30f;
    float cm = l;
    #pragma unroll
    for (int off = 32; off; off >>= 1) cm = fmaxf(cm, __shfl_xor(cm, off));
    float nm = fmaxf(m, cm);
    float e = __expf(l - nm);
    float cs = e;
    #pragma unroll
    for (int off = 32; off; off >>= 1) cs += __shfl_xor(cs, off);
    float r = __expf(m - nm);
    den = den * r + cs;
    acc *= r;
    m = nm;
    int cnt = end - p0; if (cnt > 64) cnt = 64;
    for (int j = 0; j < cnt; j++) {
      float aj = __shfl(e, j);
      int   sj = __shfl(s, j);
      acc += aj * bf2f(xs_bf[(size_t)sj * 64 + lane]);
    }
  }
  out[(size_t)wid * 64 + lane] = acc / (den + 1e-16f) + b2[lane];
}

// ================================================================ launch
extern "C" void kernel_launch(void* const* d_in, const int* in_sizes, int n_in,
                              void* d_out, int out_size, void* d_ws, size_t ws_size,
                              hipStream_t stream) {
  const float* x   = (const float*)d_in[0];
  const int*   ei  = (const int*)d_in[1];
  const float* ew  = (const float*)d_in[2];
  const float* W1  = (const float*)d_in[3];
  const float* as1 = (const float*)d_in[4];
  const float* ad1 = (const float*)d_in[5];
  const float* We1 = (const float*)d_in[6];
  const float* ae1 = (const float*)d_in[7];
  const float* b1  = (const float*)d_in[8];
  const float* W2  = (const float*)d_in[9];
  const float* as2 = (const float*)d_in[10];
  const float* ad2 = (const float*)d_in[11];
  const float* We2 = (const float*)d_in[12];
  const float* ae2 = (const float*)d_in[13];
  const float* b2  = (const float*)d_in[14];

  const int n = in_sizes[0] / 128;
  const int E = in_sizes[1] / 2;
  const int Etot = E + n;
  const int nb = (n + 255) / 256;

  char* wsb = (char*)d_ws;
  size_t off = 0;
  auto alloc = [&](size_t bytes) -> void* {
    void* p = wsb + off; off += (bytes + 255) & ~(size_t)255; return p;
  };
  u64*   packed  = (u64*)  alloc((size_t)n * 8);       // deg<<32 | sum_w_fix20
  int*   cursor  = (int*)  alloc((size_t)n * 4);       // adjacent to packed: one memset
  int*   row_ptr = (int*)  alloc((size_t)(n + 1) * 4);
  int*   part    = (int*)  alloc((size_t)nb * 4);
  int2*  col_sw  = (int2*) alloc((size_t)Etot * 8);
  u16*   xs_bf   = (u16*)  alloc((size_t)n * 128 * 2); // layer1; reused layer2 (n*64)
  float* h1      = (float*)alloc((size_t)n * 128 * 4);
  float* a_src1v = (float*)alloc((size_t)n * 2 * 4);
  float* a_dst1v = (float*)alloc((size_t)n * 2 * 4);
  float* a_src2v = (float*)alloc((size_t)n * 4);
  float* a_dst2v = (float*)alloc((size_t)n * 4);
  float* scal    = (float*)alloc(64);
  if (off > ws_size) return;

  // one memset spanning packed + cursor (adjacent allocations)
  hipMemsetAsync(packed, 0, (size_t)((char*)cursor - (char*)packed) + (size_t)n * 4, stream);

  dim3 B(256);
  k_deg<<<dim3((E + 255) / 256), B, 0, stream>>>(ei + E, ew, packed, E);
  k_part<<<dim3(nb), B, 0, stream>>>(packed, part, n);
  k_scanpart<<<1, B, 0, stream>>>(part, nb);
  k_rowptr<<<dim3(nb), B, 0, stream>>>(packed, part, row_ptr, col_sw, n);
  k_scatter<<<dim3((E + 255) / 256), B, 0, stream>>>(ei, ei + E, ew, row_ptr,
                                                     cursor, col_sw, E);
  k_scalars<<<1, 64, 0, stream>>>(We1, ae1, We2, ae2, scal);
  // layer 1
  k_gemm<2><<<dim3((n + 31) / 32, 2), B, 0, stream>>>(x, W1, xs_bf, as1, ad1,
                                                      a_src1v, a_dst1v, n);
  k_agg1<<<dim3((n * 64 + 255) / 256), B, 0, stream>>>(row_ptr, col_sw,
                                                       (const float2*)a_src1v,
                                                       (const float2*)a_dst1v,
                                                       scal, xs_bf, b1, h1, n);
  // layer 2
  k_gemm<1><<<dim3((n + 31) / 32, 1), B, 0, stream>>>(h1, W2, xs_bf, as2, ad2,
                                                      a_src2v, a_dst2v, n);
  k_agg2<<<dim3((n * 64 + 255) / 256), B, 0, stream>>>(row_ptr, col_sw, a_src2v, a_dst2v,
                                                       scal, xs_bf, b2, (float*)d_out, n);
}

// Round 5
// 246.012 us; speedup vs baseline: 1.9625x; 1.1988x over previous
//
#include <hip/hip_runtime.h>
#include <math.h>

#define NEG_SLOPE 0.2f

typedef unsigned int u32;
typedef unsigned short u16;
typedef unsigned long long u64;

__device__ __forceinline__ float bf2f(u16 h) {
  union { u32 u; float f; } c; c.u = ((u32)h) << 16; return c.f;
}
__device__ __forceinline__ u16 f2bf(float f) {
  union { float f; u32 u; } c; c.f = f;
  return (u16)((c.u + 0x7FFFu + ((c.u >> 16) & 1u)) >> 16);  // RNE, no NaNs expected
}

// ---------------------------------------------------------------- degree + edge-weight sum, packed u64 atomic, 4-way sharded
// shard s: packed[s*n + d] += (1<<32) | round(w * 2^20)
__global__ void k_deg(const int* __restrict__ dst, const float* __restrict__ ew,
                      u64* __restrict__ packed, int E, int n) {
  int e = blockIdx.x * 256 + threadIdx.x;
  if (e >= E) return;
  u32 fix = __float2uint_rn(ew[e] * 1048576.0f);
  atomicAdd(&packed[(size_t)(e & 3) * n + dst[e]], (1ULL << 32) | (u64)fix);
}

// ---------------------------------------------------------------- hierarchical scan of (deg+1) -> row_ptr
__global__ __launch_bounds__(256) void k_part(const u64* __restrict__ packed,
                                              int* __restrict__ part, int n) {
  int i = blockIdx.x * 256 + threadIdx.x;
  int v = 0;
  if (i < n) {
    u64 pk = packed[i] + packed[(size_t)n + i] + packed[2 * (size_t)n + i] + packed[3 * (size_t)n + i];
    v = (int)(pk >> 32) + 1;
  }
  #pragma unroll
  for (int off = 32; off; off >>= 1) v += __shfl_xor(v, off);
  __shared__ int ws[4];
  if ((threadIdx.x & 63) == 0) ws[threadIdx.x >> 6] = v;
  __syncthreads();
  if (threadIdx.x == 0) part[blockIdx.x] = ws[0] + ws[1] + ws[2] + ws[3];
}

__global__ __launch_bounds__(256) void k_scanpart(int* __restrict__ part, int nb) {
  __shared__ int wsum[4];
  int carry = 0;
  for (int base = 0; base < nb; base += 256) {
    int idx = base + threadIdx.x;
    int orig = (idx < nb) ? part[idx] : 0;
    int v = orig;
    #pragma unroll
    for (int off = 1; off < 64; off <<= 1) {
      int u = __shfl_up(v, off);
      if ((threadIdx.x & 63) >= off) v += u;
    }
    if ((threadIdx.x & 63) == 63) wsum[threadIdx.x >> 6] = v;
    __syncthreads();
    int w = threadIdx.x >> 6;
    int add = 0;
    if (w > 0) add += wsum[0];
    if (w > 1) add += wsum[1];
    if (w > 2) add += wsum[2];
    int excl = v - orig + add + carry;
    if (idx < nb) part[idx] = excl;
    int total = wsum[0] + wsum[1] + wsum[2] + wsum[3];
    __syncthreads();
    carry += total;
  }
}

// phase 3: row_ptr + self-loop entry (slot 0)
__global__ __launch_bounds__(256) void k_rowptr(const u64* __restrict__ packed,
                                                const int* __restrict__ part_off,
                                                int* __restrict__ row_ptr,
                                                int2* __restrict__ col_sw, int n) {
  int i = blockIdx.x * 256 + threadIdx.x;
  u64 pk = 0;
  if (i < n)
    pk = packed[i] + packed[(size_t)n + i] + packed[2 * (size_t)n + i] + packed[3 * (size_t)n + i];
  int d = (int)(pk >> 32);
  int orig = (i < n) ? d + 1 : 0;
  int v = orig;
  #pragma unroll
  for (int off = 1; off < 64; off <<= 1) {
    int u = __shfl_up(v, off);
    if ((threadIdx.x & 63) >= off) v += u;
  }
  __shared__ int wsum[4];
  if ((threadIdx.x & 63) == 63) wsum[threadIdx.x >> 6] = v;
  __syncthreads();
  int w = threadIdx.x >> 6;
  int add = 0;
  if (w > 0) add += wsum[0];
  if (w > 1) add += wsum[1];
  if (w > 2) add += wsum[2];
  if (i < n) {
    int excl = v - orig + add + part_off[blockIdx.x];
    row_ptr[i] = excl;
    float mean = ((float)(u32)pk * (1.0f / 1048576.0f)) / (float)(d > 1 ? d : 1);
    col_sw[excl] = make_int2(i, __float_as_int(mean));   // self-loop at slot 0
    if (i == n - 1) row_ptr[n] = excl + orig;
  }
}

// ---------------------------------------------------------------- counting-sort real edges into CSR slots 1..deg
__global__ void k_scatter(const int* __restrict__ src, const int* __restrict__ dst,
                          const float* __restrict__ ew,
                          const int* __restrict__ row_ptr, int* __restrict__ cursor,
                          int2* __restrict__ col_sw, int E) {
  int e = blockIdx.x * 256 + threadIdx.x;
  if (e >= E) return;
  int d = dst[e];
  int p = row_ptr[d] + 1 + atomicAdd(&cursor[d], 1);
  col_sw[p] = make_int2(src[e], __float_as_int(ew[e]));
}

// ---------------------------------------------------------------- f32 GEMM (K=128) + bf16 store + fused attn dots
template<int H>
__global__ __launch_bounds__(256) void k_gemm(const float* __restrict__ A,
                                              const float* __restrict__ B,
                                              u16* __restrict__ xs_bf,
                                              const float* __restrict__ att_src,
                                              const float* __restrict__ att_dst,
                                              float* __restrict__ a_src_out,
                                              float* __restrict__ a_dst_out,
                                              int nrows) {
  const int ncols = H * 64;
  __shared__ float Bs[128 * 64];
  int h = blockIdx.y;
  int c0 = h * 64;
  for (int i = threadIdx.x; i < 128 * 16; i += 256) {
    int k = i >> 4, c4 = (i & 15) << 2;
    *(float4*)&Bs[k * 64 + c4] = *(const float4*)&B[(size_t)k * ncols + c0 + c4];
  }
  __syncthreads();
  int rp = threadIdx.x >> 4;
  int cq = (threadIdx.x & 15) << 2;
  int r0 = blockIdx.x * 32 + rp * 2, r1 = r0 + 1;
  bool v0 = r0 < nrows, v1 = r1 < nrows;
  const float4* A0 = (const float4*)(A + (size_t)(v0 ? r0 : 0) * 128);
  const float4* A1 = (const float4*)(A + (size_t)(v1 ? r1 : 0) * 128);
  float4 acc0 = {0,0,0,0}, acc1 = {0,0,0,0};
  #pragma unroll 8
  for (int k4 = 0; k4 < 32; k4++) {
    float4 a0 = A0[k4], a1 = A1[k4];
    float a0s[4] = {a0.x, a0.y, a0.z, a0.w};
    float a1s[4] = {a1.x, a1.y, a1.z, a1.w};
    #pragma unroll
    for (int kk = 0; kk < 4; kk++) {
      float4 b = *(const float4*)&Bs[(4 * k4 + kk) * 64 + cq];
      acc0.x += a0s[kk] * b.x; acc0.y += a0s[kk] * b.y;
      acc0.z += a0s[kk] * b.z; acc0.w += a0s[kk] * b.w;
      acc1.x += a1s[kk] * b.x; acc1.y += a1s[kk] * b.y;
      acc1.z += a1s[kk] * b.z; acc1.w += a1s[kk] * b.w;
    }
  }
  if (v0) {
    ushort4 o = { f2bf(acc0.x), f2bf(acc0.y), f2bf(acc0.z), f2bf(acc0.w) };
    *(ushort4*)&xs_bf[(size_t)r0 * ncols + c0 + cq] = o;
  }
  if (v1) {
    ushort4 o = { f2bf(acc1.x), f2bf(acc1.y), f2bf(acc1.z), f2bf(acc1.w) };
    *(ushort4*)&xs_bf[(size_t)r1 * ncols + c0 + cq] = o;
  }
  float4 as = *(const float4*)&att_src[c0 + cq];
  float4 ad = *(const float4*)&att_dst[c0 + cq];
  float ps0 = acc0.x*as.x + acc0.y*as.y + acc0.z*as.z + acc0.w*as.w;
  float pd0 = acc0.x*ad.x + acc0.y*ad.y + acc0.z*ad.z + acc0.w*ad.w;
  float ps1 = acc1.x*as.x + acc1.y*as.y + acc1.z*as.z + acc1.w*as.w;
  float pd1 = acc1.x*ad.x + acc1.y*ad.y + acc1.z*ad.z + acc1.w*ad.w;
  #pragma unroll
  for (int off = 8; off; off >>= 1) {
    ps0 += __shfl_xor(ps0, off); pd0 += __shfl_xor(pd0, off);
    ps1 += __shfl_xor(ps1, off); pd1 += __shfl_xor(pd1, off);
  }
  if ((threadIdx.x & 15) == 0) {
    if (v0) { a_src_out[r0 * H + h] = ps0; a_dst_out[r0 * H + h] = pd0; }
    if (v1) { a_src_out[r1 * H + h] = ps1; a_dst_out[r1 * H + h] = pd1; }
  }
}

// ---------------------------------------------------------------- edge-attention scalars
__global__ void k_scalars(const float* __restrict__ We1, const float* __restrict__ ae1,
                          const float* __restrict__ We2, const float* __restrict__ ae2,
                          float* __restrict__ out) {
  int t = threadIdx.x;
  if (t == 0) { float s = 0; for (int c = 0; c < 64; c++) s += We1[c] * ae1[c]; out[0] = s; }
  if (t == 1) { float s = 0; for (int c = 0; c < 64; c++) s += We1[64 + c] * ae1[64 + c]; out[1] = s; }
  if (t == 2) { float s = 0; for (int c = 0; c < 64; c++) s += We2[c] * ae2[c]; out[2] = s; }
}

// ---------------------------------------------------------------- layer 1 agg: 16-lane group per node (4 nodes/wave)
// group-lane gl owns features 8gl..8gl+7 (gl<8: head0, gl>=8: head1); edge phase: gl owns edge beg+gl (+16 chunks)
__global__ __launch_bounds__(256) void k_agg1(const int* __restrict__ row_ptr,
                                              const int2* __restrict__ col_sw,
                                              const float2* __restrict__ a_src,
                                              const float2* __restrict__ a_dst,
                                              const float* __restrict__ scal,
                                              const u16* __restrict__ xs_bf,
                                              const float* __restrict__ b1,
                                              float* __restrict__ h_out, int n) {
  int wid = (blockIdx.x * 256 + threadIdx.x) >> 4;
  int gl = threadIdx.x & 15;
  if (wid >= n) return;
  int beg = row_ptr[wid], end = row_ptr[wid + 1];
  float2 ad = a_dst[wid];
  float sc0 = scal[0], sc1 = scal[1];
  bool hi = gl >= 8;
  float m0 = -1e30f, m1 = -1e30f, den0 = 0.f, den1 = 0.f;
  float acc[8] = {0.f, 0.f, 0.f, 0.f, 0.f, 0.f, 0.f, 0.f};
  for (int p0 = beg; p0 < end; p0 += 16) {
    int p = p0 + gl;
    bool act = p < end;
    int2 sw = col_sw[act ? p : beg];
    int s = sw.x;
    float w = __int_as_float(sw.y);
    float2 asv = a_src[s];
    float l0 = asv.x + ad.x + w * sc0;
    float l1 = asv.y + ad.y + w * sc1;
    l0 = l0 > 0.f ? l0 : NEG_SLOPE * l0;
    l1 = l1 > 0.f ? l1 : NEG_SLOPE * l1;
    if (!act) { l0 = -1e30f; l1 = -1e30f; }
    float cm0 = l0, cm1 = l1;
    #pragma unroll
    for (int off = 8; off; off >>= 1) {
      cm0 = fmaxf(cm0, __shfl_xor(cm0, off, 16));
      cm1 = fmaxf(cm1, __shfl_xor(cm1, off, 16));
    }
    float nm0 = fmaxf(m0, cm0), nm1 = fmaxf(m1, cm1);
    float e0 = __expf(l0 - nm0), e1 = __expf(l1 - nm1);
    float cs0 = e0, cs1 = e1;
    #pragma unroll
    for (int off = 8; off; off >>= 1) {
      cs0 += __shfl_xor(cs0, off, 16);
      cs1 += __shfl_xor(cs1, off, 16);
    }
    float r0 = __expf(m0 - nm0), r1 = __expf(m1 - nm1);
    den0 = den0 * r0 + cs0;
    den1 = den1 * r1 + cs1;
    float rs = hi ? r1 : r0;
    #pragma unroll
    for (int f = 0; f < 8; f++) acc[f] *= rs;
    m0 = nm0; m1 = nm1;
    int cnt = end - p0; if (cnt > 16) cnt = 16;
    for (int j = 0; j < cnt; j++) {
      float a0 = __shfl(e0, j, 16);
      float a1 = __shfl(e1, j, 16);
      int   sj = __shfl(s, j, 16);
      uint4 q = *(const uint4*)&xs_bf[(size_t)sj * 128 + 8 * gl];
      float al = hi ? a1 : a0;
      acc[0] += al * bf2f((u16)q.x); acc[1] += al * bf2f((u16)(q.x >> 16));
      acc[2] += al * bf2f((u16)q.y); acc[3] += al * bf2f((u16)(q.y >> 16));
      acc[4] += al * bf2f((u16)q.z); acc[5] += al * bf2f((u16)(q.z >> 16));
      acc[6] += al * bf2f((u16)q.w); acc[7] += al * bf2f((u16)(q.w >> 16));
    }
  }
  float inv = 1.f / ((hi ? den1 : den0) + 1e-16f);
  float4 blo = *(const float4*)&b1[8 * gl];
  float4 bhi = *(const float4*)&b1[8 * gl + 4];
  float o[8];
  o[0] = acc[0] * inv + blo.x; o[1] = acc[1] * inv + blo.y;
  o[2] = acc[2] * inv + blo.z; o[3] = acc[3] * inv + blo.w;
  o[4] = acc[4] * inv + bhi.x; o[5] = acc[5] * inv + bhi.y;
  o[6] = acc[6] * inv + bhi.z; o[7] = acc[7] * inv + bhi.w;
  #pragma unroll
  for (int f = 0; f < 8; f++) o[f] = o[f] > 0.f ? o[f] : expm1f(o[f]);   // ELU
  float* dst = &h_out[(size_t)wid * 128 + 8 * gl];
  *(float4*)dst = make_float4(o[0], o[1], o[2], o[3]);
  *(float4*)(dst + 4) = make_float4(o[4], o[5], o[6], o[7]);
}

// ---------------------------------------------------------------- layer 2 agg: 16-lane group per node, 4 features/lane
__global__ __launch_bounds__(256) void k_agg2(const int* __restrict__ row_ptr,
                                              const int2* __restrict__ col_sw,
                                              const float* __restrict__ a_src,
                                              const float* __restrict__ a_dst,
                                              const float* __restrict__ scal,
                                              const u16* __restrict__ xs_bf,
                                              const float* __restrict__ b2,
                                              float* __restrict__ out, int n) {
  int wid = (blockIdx.x * 256 + threadIdx.x) >> 4;
  int gl = threadIdx.x & 15;
  if (wid >= n) return;
  int beg = row_ptr[wid], end = row_ptr[wid + 1];
  float adv = a_dst[wid];
  float sc = scal[2];
  float m = -1e30f, den = 0.f;
  float acc[4] = {0.f, 0.f, 0.f, 0.f};
  for (int p0 = beg; p0 < end; p0 += 16) {
    int p = p0 + gl;
    bool act = p < end;
    int2 sw = col_sw[act ? p : beg];
    int s = sw.x;
    float w = __int_as_float(sw.y);
    float l = a_src[s] + adv + w * sc;
    l = l > 0.f ? l : NEG_SLOPE * l;
    if (!act) l = -1e30f;
    float cm = l;
    #pragma unroll
    for (int off = 8; off; off >>= 1) cm = fmaxf(cm, __shfl_xor(cm, off, 16));
    float nm = fmaxf(m, cm);
    float e = __expf(l - nm);
    float cs = e;
    #pragma unroll
    for (int off = 8; off; off >>= 1) cs += __shfl_xor(cs, off, 16);
    float r = __expf(m - nm);
    den = den * r + cs;
    #pragma unroll
    for (int f = 0; f < 4; f++) acc[f] *= r;
    m = nm;
    int cnt = end - p0; if (cnt > 16) cnt = 16;
    for (int j = 0; j < cnt; j++) {
      float aj = __shfl(e, j, 16);
      int   sj = __shfl(s, j, 16);
      uint2 q = *(const uint2*)&xs_bf[(size_t)sj * 64 + 4 * gl];
      acc[0] += aj * bf2f((u16)q.x); acc[1] += aj * bf2f((u16)(q.x >> 16));
      acc[2] += aj * bf2f((u16)q.y); acc[3] += aj * bf2f((u16)(q.y >> 16));
    }
  }
  float inv = 1.f / (den + 1e-16f);
  float4 b = *(const float4*)&b2[4 * gl];
  *(float4*)&out[(size_t)wid * 64 + 4 * gl] =
      make_float4(acc[0] * inv + b.x, acc[1] * inv + b.y,
                  acc[2] * inv + b.z, acc[3] * inv + b.w);
}

// ================================================================ launch
extern "C" void kernel_launch(void* const* d_in, const int* in_sizes, int n_in,
                              void* d_out, int out_size, void* d_ws, size_t ws_size,
                              hipStream_t stream) {
  const float* x   = (const float*)d_in[0];
  const int*   ei  = (const int*)d_in[1];
  const float* ew  = (const float*)d_in[2];
  const float* W1  = (const float*)d_in[3];
  const float* as1 = (const float*)d_in[4];
  const float* ad1 = (const float*)d_in[5];
  const float* We1 = (const float*)d_in[6];
  const float* ae1 = (const float*)d_in[7];
  const float* b1  = (const float*)d_in[8];
  const float* W2  = (const float*)d_in[9];
  const float* as2 = (const float*)d_in[10];
  const float* ad2 = (const float*)d_in[11];
  const float* We2 = (const float*)d_in[12];
  const float* ae2 = (const float*)d_in[13];
  const float* b2  = (const float*)d_in[14];

  const int n = in_sizes[0] / 128;
  const int E = in_sizes[1] / 2;
  const int Etot = E + n;
  const int nb = (n + 255) / 256;

  char* wsb = (char*)d_ws;
  size_t off = 0;
  auto alloc = [&](size_t bytes) -> void* {
    void* p = wsb + off; off += (bytes + 255) & ~(size_t)255; return p;
  };
  u64*   packed  = (u64*)  alloc((size_t)n * 4 * 8);   // 4 shards: deg<<32 | sum_w_fix20
  int*   cursor  = (int*)  alloc((size_t)n * 4);       // adjacent to packed: one memset
  int*   row_ptr = (int*)  alloc((size_t)(n + 1) * 4);
  int*   part    = (int*)  alloc((size_t)nb * 4);
  int2*  col_sw  = (int2*) alloc((size_t)Etot * 8);
  u16*   xs_bf   = (u16*)  alloc((size_t)n * 128 * 2); // layer1; reused layer2 (n*64)
  float* h1      = (float*)alloc((size_t)n * 128 * 4);
  float* a_src1v = (float*)alloc((size_t)n * 2 * 4);
  float* a_dst1v = (float*)alloc((size_t)n * 2 * 4);
  float* a_src2v = (float*)alloc((size_t)n * 4);
  float* a_dst2v = (float*)alloc((size_t)n * 4);
  float* scal    = (float*)alloc(64);
  if (off > ws_size) return;

  hipMemsetAsync(packed, 0, (size_t)((char*)cursor - (char*)packed) + (size_t)n * 4, stream);

  dim3 B(256);
  k_deg<<<dim3((E + 255) / 256), B, 0, stream>>>(ei + E, ew, packed, E, n);
  k_part<<<dim3(nb), B, 0, stream>>>(packed, part, n);
  k_scanpart<<<1, B, 0, stream>>>(part, nb);
  k_rowptr<<<dim3(nb), B, 0, stream>>>(packed, part, row_ptr, col_sw, n);
  k_scatter<<<dim3((E + 255) / 256), B, 0, stream>>>(ei, ei + E, ew, row_ptr,
                                                     cursor, col_sw, E);
  k_scalars<<<1, 64, 0, stream>>>(We1, ae1, We2, ae2, scal);
  // layer 1
  k_gemm<2><<<dim3((n + 31) / 32, 2), B, 0, stream>>>(x, W1, xs_bf, as1, ad1,
                                                      a_src1v, a_dst1v, n);
  k_agg1<<<dim3((n + 15) / 16), B, 0, stream>>>(row_ptr, col_sw,
                                                (const float2*)a_src1v,
                                                (const float2*)a_dst1v,
                                                scal, xs_bf, b1, h1, n);
  // layer 2
  k_gemm<1><<<dim3((n + 31) / 32, 1), B, 0, stream>>>(h1, W2, xs_bf, as2, ad2,
                                                      a_src2v, a_dst2v, n);
  k_agg2<<<dim3((n + 15) / 16), B, 0, stream>>>(row_ptr, col_sw, a_src2v, a_dst2v,
                                                scal, xs_bf, b2, (float*)d_out, n);
}

// Round 6
// 201.555 us; speedup vs baseline: 2.3954x; 1.2206x over previous
//
#include <hip/hip_runtime.h>
#include <math.h>

#define NEG_SLOPE 0.2f

typedef unsigned int u32;
typedef unsigned short u16;
typedef unsigned long long u64;

__device__ __forceinline__ float bf2f(u16 h) {
  union { u32 u; float f; } c; c.u = ((u32)h) << 16; return c.f;
}
__device__ __forceinline__ u16 f2bf(float f) {
  union { float f; u32 u; } c; c.f = f;
  return (u16)((c.u + 0x7FFFu + ((c.u >> 16) & 1u)) >> 16);  // RNE, no NaNs expected
}

// ---------------------------------------------------------------- degree + edge-weight sum, packed u64 atomic, 4-way sharded
// shard s=e&3: packed[s*n + d] += (1<<32) | round(w * 2^20); atomic return gives the edge's rank in (d,s)
__global__ void k_deg(const int* __restrict__ dst, const float* __restrict__ ew,
                      u64* __restrict__ packed, u16* __restrict__ rank, int E, int n) {
  int e = blockIdx.x * 256 + threadIdx.x;
  if (e >= E) return;
  u32 fix = __float2uint_rn(ew[e] * 1048576.0f);
  u64 old = atomicAdd(&packed[(size_t)(e & 3) * n + dst[e]], (1ULL << 32) | (u64)fix);
  rank[e] = (u16)(old >> 32);
}

// ---------------------------------------------------------------- hierarchical scan of (deg+1) -> row_ptr
__global__ __launch_bounds__(256) void k_part(const u64* __restrict__ packed,
                                              int* __restrict__ part, int n) {
  int i = blockIdx.x * 256 + threadIdx.x;
  int v = 0;
  if (i < n) {
    u64 pk = packed[i] + packed[(size_t)n + i] + packed[2 * (size_t)n + i] + packed[3 * (size_t)n + i];
    v = (int)(pk >> 32) + 1;
  }
  #pragma unroll
  for (int off = 32; off; off >>= 1) v += __shfl_xor(v, off);
  __shared__ int ws[4];
  if ((threadIdx.x & 63) == 0) ws[threadIdx.x >> 6] = v;
  __syncthreads();
  if (threadIdx.x == 0) part[blockIdx.x] = ws[0] + ws[1] + ws[2] + ws[3];
}

__global__ __launch_bounds__(256) void k_scanpart(int* __restrict__ part, int nb) {
  __shared__ int wsum[4];
  int carry = 0;
  for (int base = 0; base < nb; base += 256) {
    int idx = base + threadIdx.x;
    int orig = (idx < nb) ? part[idx] : 0;
    int v = orig;
    #pragma unroll
    for (int off = 1; off < 64; off <<= 1) {
      int u = __shfl_up(v, off);
      if ((threadIdx.x & 63) >= off) v += u;
    }
    if ((threadIdx.x & 63) == 63) wsum[threadIdx.x >> 6] = v;
    __syncthreads();
    int w = threadIdx.x >> 6;
    int add = 0;
    if (w > 0) add += wsum[0];
    if (w > 1) add += wsum[1];
    if (w > 2) add += wsum[2];
    int excl = v - orig + add + carry;
    if (idx < nb) part[idx] = excl;
    int total = wsum[0] + wsum[1] + wsum[2] + wsum[3];
    __syncthreads();
    carry += total;
  }
}

// phase 3: row_ptr + per-shard base offsets + self-loop entry (slot 0, packed u32)
__global__ __launch_bounds__(256) void k_rowptr(const u64* __restrict__ packed,
                                                const int* __restrict__ part_off,
                                                int* __restrict__ row_ptr,
                                                int4* __restrict__ base4,
                                                u32* __restrict__ col, int n) {
  int i = blockIdx.x * 256 + threadIdx.x;
  u64 q0 = 0, q1 = 0, q2 = 0, q3 = 0;
  if (i < n) {
    q0 = packed[i]; q1 = packed[(size_t)n + i];
    q2 = packed[2 * (size_t)n + i]; q3 = packed[3 * (size_t)n + i];
  }
  int c0 = (int)(q0 >> 32), c1 = (int)(q1 >> 32), c2 = (int)(q2 >> 32), c3 = (int)(q3 >> 32);
  int d = c0 + c1 + c2 + c3;
  u32 sumfix = (u32)q0 + (u32)q1 + (u32)q2 + (u32)q3;   // < 2^28, no overflow
  int orig = (i < n) ? d + 1 : 0;
  int v = orig;
  #pragma unroll
  for (int off = 1; off < 64; off <<= 1) {
    int u = __shfl_up(v, off);
    if ((threadIdx.x & 63) >= off) v += u;
  }
  __shared__ int wsum[4];
  if ((threadIdx.x & 63) == 63) wsum[threadIdx.x >> 6] = v;
  __syncthreads();
  int w = threadIdx.x >> 6;
  int add = 0;
  if (w > 0) add += wsum[0];
  if (w > 1) add += wsum[1];
  if (w > 2) add += wsum[2];
  if (i < n) {
    int excl = v - orig + add + part_off[blockIdx.x];
    row_ptr[i] = excl;
    int b = excl + 1;
    base4[i] = make_int4(b, b + c0, b + c0 + c1, b + c0 + c1 + c2);
    float mean = ((float)sumfix * (1.0f / 1048576.0f)) / (float)(d > 1 ? d : 1);
    u32 wq = (u32)(mean * 65536.0f); if (wq > 65535u) wq = 65535u;
    col[excl] = (u32)i | (wq << 16);                     // self-loop at slot 0
    if (i == n - 1) row_ptr[n] = excl + orig;
  }
}

// ---------------------------------------------------------------- place real edges into CSR slots (no atomics)
__global__ void k_scatter(const int* __restrict__ src, const int* __restrict__ dst,
                          const float* __restrict__ ew, const u16* __restrict__ rank,
                          const int* __restrict__ base4,
                          u32* __restrict__ col, int E) {
  int e = blockIdx.x * 256 + threadIdx.x;
  if (e >= E) return;
  int p = base4[4 * dst[e] + (e & 3)] + rank[e];
  u32 wq = (u32)(ew[e] * 65536.0f); if (wq > 65535u) wq = 65535u;
  col[p] = (u32)src[e] | (wq << 16);
}

// ---------------------------------------------------------------- f32 GEMM (K=128) + bf16 store + fused attn dots
template<int H>
__global__ __launch_bounds__(256) void k_gemm(const float* __restrict__ A,
                                              const float* __restrict__ B,
                                              u16* __restrict__ xs_bf,
                                              const float* __restrict__ att_src,
                                              const float* __restrict__ att_dst,
                                              float* __restrict__ a_src_out,
                                              float* __restrict__ a_dst_out,
                                              int nrows) {
  const int ncols = H * 64;
  __shared__ float Bs[128 * 64];
  int h = blockIdx.y;
  int c0 = h * 64;
  for (int i = threadIdx.x; i < 128 * 16; i += 256) {
    int k = i >> 4, c4 = (i & 15) << 2;
    *(float4*)&Bs[k * 64 + c4] = *(const float4*)&B[(size_t)k * ncols + c0 + c4];
  }
  __syncthreads();
  int rp = threadIdx.x >> 4;
  int cq = (threadIdx.x & 15) << 2;
  int r0 = blockIdx.x * 32 + rp * 2, r1 = r0 + 1;
  bool v0 = r0 < nrows, v1 = r1 < nrows;
  const float4* A0 = (const float4*)(A + (size_t)(v0 ? r0 : 0) * 128);
  const float4* A1 = (const float4*)(A + (size_t)(v1 ? r1 : 0) * 128);
  float4 acc0 = {0,0,0,0}, acc1 = {0,0,0,0};
  #pragma unroll 8
  for (int k4 = 0; k4 < 32; k4++) {
    float4 a0 = A0[k4], a1 = A1[k4];
    float a0s[4] = {a0.x, a0.y, a0.z, a0.w};
    float a1s[4] = {a1.x, a1.y, a1.z, a1.w};
    #pragma unroll
    for (int kk = 0; kk < 4; kk++) {
      float4 b = *(const float4*)&Bs[(4 * k4 + kk) * 64 + cq];
      acc0.x += a0s[kk] * b.x; acc0.y += a0s[kk] * b.y;
      acc0.z += a0s[kk] * b.z; acc0.w += a0s[kk] * b.w;
      acc1.x += a1s[kk] * b.x; acc1.y += a1s[kk] * b.y;
      acc1.z += a1s[kk] * b.z; acc1.w += a1s[kk] * b.w;
    }
  }
  if (v0) {
    ushort4 o = { f2bf(acc0.x), f2bf(acc0.y), f2bf(acc0.z), f2bf(acc0.w) };
    *(ushort4*)&xs_bf[(size_t)r0 * ncols + c0 + cq] = o;
  }
  if (v1) {
    ushort4 o = { f2bf(acc1.x), f2bf(acc1.y), f2bf(acc1.z), f2bf(acc1.w) };
    *(ushort4*)&xs_bf[(size_t)r1 * ncols + c0 + cq] = o;
  }
  float4 as = *(const float4*)&att_src[c0 + cq];
  float4 ad = *(const float4*)&att_dst[c0 + cq];
  float ps0 = acc0.x*as.x + acc0.y*as.y + acc0.z*as.z + acc0.w*as.w;
  float pd0 = acc0.x*ad.x + acc0.y*ad.y + acc0.z*ad.z + acc0.w*ad.w;
  float ps1 = acc1.x*as.x + acc1.y*as.y + acc1.z*as.z + acc1.w*as.w;
  float pd1 = acc1.x*ad.x + acc1.y*ad.y + acc1.z*ad.z + acc1.w*ad.w;
  #pragma unroll
  for (int off = 8; off; off >>= 1) {
    ps0 += __shfl_xor(ps0, off); pd0 += __shfl_xor(pd0, off);
    ps1 += __shfl_xor(ps1, off); pd1 += __shfl_xor(pd1, off);
  }
  if ((threadIdx.x & 15) == 0) {
    if (v0) { a_src_out[r0 * H + h] = ps0; a_dst_out[r0 * H + h] = pd0; }
    if (v1) { a_src_out[r1 * H + h] = ps1; a_dst_out[r1 * H + h] = pd1; }
  }
}

// ---------------------------------------------------------------- edge-attention scalars
__global__ void k_scalars(const float* __restrict__ We1, const float* __restrict__ ae1,
                          const float* __restrict__ We2, const float* __restrict__ ae2,
                          float* __restrict__ out) {
  int t = threadIdx.x;
  if (t == 0) { float s = 0; for (int c = 0; c < 64; c++) s += We1[c] * ae1[c]; out[0] = s; }
  if (t == 1) { float s = 0; for (int c = 0; c < 64; c++) s += We1[64 + c] * ae1[64 + c]; out[1] = s; }
  if (t == 2) { float s = 0; for (int c = 0; c < 64; c++) s += We2[c] * ae2[c]; out[2] = s; }
}

// ---------------------------------------------------------------- layer 1 agg: 16-lane group per node (4 nodes/wave)
__global__ __launch_bounds__(256) void k_agg1(const int* __restrict__ row_ptr,
                                              const u32* __restrict__ col,
                                              const float2* __restrict__ a_src,
                                              const float2* __restrict__ a_dst,
                                              const float* __restrict__ scal,
                                              const u16* __restrict__ xs_bf,
                                              const float* __restrict__ b1,
                                              float* __restrict__ h_out, int n) {
  int wid = (blockIdx.x * 256 + threadIdx.x) >> 4;
  int gl = threadIdx.x & 15;
  if (wid >= n) return;
  int beg = row_ptr[wid], end = row_ptr[wid + 1];
  float2 ad = a_dst[wid];
  float sc0 = scal[0], sc1 = scal[1];
  bool hi = gl >= 8;
  float m0 = -1e30f, m1 = -1e30f, den0 = 0.f, den1 = 0.f;
  float acc[8] = {0.f, 0.f, 0.f, 0.f, 0.f, 0.f, 0.f, 0.f};
  for (int p0 = beg; p0 < end; p0 += 16) {
    int p = p0 + gl;
    bool act = p < end;
    u32 sw = col[act ? p : beg];
    int s = (int)(sw & 0xFFFFu);
    float w = (float)(sw >> 16) * (1.0f / 65536.0f);
    float2 asv = a_src[s];
    float l0 = asv.x + ad.x + w * sc0;
    float l1 = asv.y + ad.y + w * sc1;
    l0 = l0 > 0.f ? l0 : NEG_SLOPE * l0;
    l1 = l1 > 0.f ? l1 : NEG_SLOPE * l1;
    if (!act) { l0 = -1e30f; l1 = -1e30f; }
    float cm0 = l0, cm1 = l1;
    #pragma unroll
    for (int off = 8; off; off >>= 1) {
      cm0 = fmaxf(cm0, __shfl_xor(cm0, off, 16));
      cm1 = fmaxf(cm1, __shfl_xor(cm1, off, 16));
    }
    float nm0 = fmaxf(m0, cm0), nm1 = fmaxf(m1, cm1);
    float e0 = __expf(l0 - nm0), e1 = __expf(l1 - nm1);
    float cs0 = e0, cs1 = e1;
    #pragma unroll
    for (int off = 8; off; off >>= 1) {
      cs0 += __shfl_xor(cs0, off, 16);
      cs1 += __shfl_xor(cs1, off, 16);
    }
    float r0 = __expf(m0 - nm0), r1 = __expf(m1 - nm1);
    den0 = den0 * r0 + cs0;
    den1 = den1 * r1 + cs1;
    float rs = hi ? r1 : r0;
    #pragma unroll
    for (int f = 0; f < 8; f++) acc[f] *= rs;
    m0 = nm0; m1 = nm1;
    int cnt = end - p0; if (cnt > 16) cnt = 16;
    for (int j = 0; j < cnt; j++) {
      float a0 = __shfl(e0, j, 16);
      float a1 = __shfl(e1, j, 16);
      int   sj = __shfl(s, j, 16);
      uint4 q = *(const uint4*)&xs_bf[(size_t)sj * 128 + 8 * gl];
      float al = hi ? a1 : a0;
      acc[0] += al * bf2f((u16)q.x); acc[1] += al * bf2f((u16)(q.x >> 16));
      acc[2] += al * bf2f((u16)q.y); acc[3] += al * bf2f((u16)(q.y >> 16));
      acc[4] += al * bf2f((u16)q.z); acc[5] += al * bf2f((u16)(q.z >> 16));
      acc[6] += al * bf2f((u16)q.w); acc[7] += al * bf2f((u16)(q.w >> 16));
    }
  }
  float inv = 1.f / ((hi ? den1 : den0) + 1e-16f);
  float4 blo = *(const float4*)&b1[8 * gl];
  float4 bhi = *(const float4*)&b1[8 * gl + 4];
  float o[8];
  o[0] = acc[0] * inv + blo.x; o[1] = acc[1] * inv + blo.y;
  o[2] = acc[2] * inv + blo.z; o[3] = acc[3] * inv + blo.w;
  o[4] = acc[4] * inv + bhi.x; o[5] = acc[5] * inv + bhi.y;
  o[6] = acc[6] * inv + bhi.z; o[7] = acc[7] * inv + bhi.w;
  #pragma unroll
  for (int f = 0; f < 8; f++) o[f] = o[f] > 0.f ? o[f] : expm1f(o[f]);   // ELU
  float* dst = &h_out[(size_t)wid * 128 + 8 * gl];
  *(float4*)dst = make_float4(o[0], o[1], o[2], o[3]);
  *(float4*)(dst + 4) = make_float4(o[4], o[5], o[6], o[7]);
}

// ---------------------------------------------------------------- layer 2 agg: 16-lane group per node, 4 features/lane
__global__ __launch_bounds__(256) void k_agg2(const int* __restrict__ row_ptr,
                                              const u32* __restrict__ col,
                                              const float* __restrict__ a_src,
                                              const float* __restrict__ a_dst,
                                              const float* __restrict__ scal,
                                              const u16* __restrict__ xs_bf,
                                              const float* __restrict__ b2,
                                              float* __restrict__ out, int n) {
  int wid = (blockIdx.x * 256 + threadIdx.x) >> 4;
  int gl = threadIdx.x & 15;
  if (wid >= n) return;
  int beg = row_ptr[wid], end = row_ptr[wid + 1];
  float adv = a_dst[wid];
  float sc = scal[2];
  float m = -1e30f, den = 0.f;
  float acc[4] = {0.f, 0.f, 0.f, 0.f};
  for (int p0 = beg; p0 < end; p0 += 16) {
    int p = p0 + gl;
    bool act = p < end;
    u32 sw = col[act ? p : beg];
    int s = (int)(sw & 0xFFFFu);
    float w = (float)(sw >> 16) * (1.0f / 65536.0f);
    float l = a_src[s] + adv + w * sc;
    l = l > 0.f ? l : NEG_SLOPE * l;
    if (!act) l = -1e30f;
    float cm = l;
    #pragma unroll
    for (int off = 8; off; off >>= 1) cm = fmaxf(cm, __shfl_xor(cm, off, 16));
    float nm = fmaxf(m, cm);
    float e = __expf(l - nm);
    float cs = e;
    #pragma unroll
    for (int off = 8; off; off >>= 1) cs += __shfl_xor(cs, off, 16);
    float r = __expf(m - nm);
    den = den * r + cs;
    #pragma unroll
    for (int f = 0; f < 4; f++) acc[f] *= r;
    m = nm;
    int cnt = end - p0; if (cnt > 16) cnt = 16;
    for (int j = 0; j < cnt; j++) {
      float aj = __shfl(e, j, 16);
      int   sj = __shfl(s, j, 16);
      uint2 q = *(const uint2*)&xs_bf[(size_t)sj * 64 + 4 * gl];
      acc[0] += aj * bf2f((u16)q.x); acc[1] += aj * bf2f((u16)(q.x >> 16));
      acc[2] += aj * bf2f((u16)q.y); acc[3] += aj * bf2f((u16)(q.y >> 16));
    }
  }
  float inv = 1.f / (den + 1e-16f);
  float4 b = *(const float4*)&b2[4 * gl];
  *(float4*)&out[(size_t)wid * 64 + 4 * gl] =
      make_float4(acc[0] * inv + b.x, acc[1] * inv + b.y,
                  acc[2] * inv + b.z, acc[3] * inv + b.w);
}

// ================================================================ launch
extern "C" void kernel_launch(void* const* d_in, const int* in_sizes, int n_in,
                              void* d_out, int out_size, void* d_ws, size_t ws_size,
                              hipStream_t stream) {
  const float* x   = (const float*)d_in[0];
  const int*   ei  = (const int*)d_in[1];
  const float* ew  = (const float*)d_in[2];
  const float* W1  = (const float*)d_in[3];
  const float* as1 = (const float*)d_in[4];
  const float* ad1 = (const float*)d_in[5];
  const float* We1 = (const float*)d_in[6];
  const float* ae1 = (const float*)d_in[7];
  const float* b1  = (const float*)d_in[8];
  const float* W2  = (const float*)d_in[9];
  const float* as2 = (const float*)d_in[10];
  const float* ad2 = (const float*)d_in[11];
  const float* We2 = (const float*)d_in[12];
  const float* ae2 = (const float*)d_in[13];
  const float* b2  = (const float*)d_in[14];

  const int n = in_sizes[0] / 128;
  const int E = in_sizes[1] / 2;
  const int Etot = E + n;
  const int nb = (n + 255) / 256;

  char* wsb = (char*)d_ws;
  size_t off = 0;
  auto alloc = [&](size_t bytes) -> void* {
    void* p = wsb + off; off += (bytes + 255) & ~(size_t)255; return p;
  };
  u64*   packed  = (u64*)  alloc((size_t)n * 4 * 8);   // 4 shards: deg<<32 | sum_w_fix20
  u16*   rank    = (u16*)  alloc((size_t)E * 2);
  int*   row_ptr = (int*)  alloc((size_t)(n + 1) * 4);
  int*   base4   = (int*)  alloc((size_t)n * 4 * 4);   // per-(dst,shard) absolute CSR base
  int*   part    = (int*)  alloc((size_t)nb * 4);
  u32*   col     = (u32*)  alloc((size_t)Etot * 4);    // src:16 | wq:16
  u16*   xs_bf   = (u16*)  alloc((size_t)n * 128 * 2); // layer1; reused layer2 (n*64)
  float* h1      = (float*)alloc((size_t)n * 128 * 4);
  float* a_src1v = (float*)alloc((size_t)n * 2 * 4);
  float* a_dst1v = (float*)alloc((size_t)n * 2 * 4);
  float* a_src2v = (float*)alloc((size_t)n * 4);
  float* a_dst2v = (float*)alloc((size_t)n * 4);
  float* scal    = (float*)alloc(64);
  if (off > ws_size) return;

  hipMemsetAsync(packed, 0, (size_t)n * 4 * 8, stream);

  dim3 B(256);
  k_deg<<<dim3((E + 255) / 256), B, 0, stream>>>(ei + E, ew, packed, rank, E, n);
  k_part<<<dim3(nb), B, 0, stream>>>(packed, part, n);
  k_scanpart<<<1, B, 0, stream>>>(part, nb);
  k_rowptr<<<dim3(nb), B, 0, stream>>>(packed, part, row_ptr, (int4*)base4, col, n);
  k_scatter<<<dim3((E + 255) / 256), B, 0, stream>>>(ei, ei + E, ew, rank, base4, col, E);
  k_scalars<<<1, 64, 0, stream>>>(We1, ae1, We2, ae2, scal);
  // layer 1
  k_gemm<2><<<dim3((n + 31) / 32, 2), B, 0, stream>>>(x, W1, xs_bf, as1, ad1,
                                                      a_src1v, a_dst1v, n);
  k_agg1<<<dim3((n + 15) / 16), B, 0, stream>>>(row_ptr, col,
                                                (const float2*)a_src1v,
                                                (const float2*)a_dst1v,
                                                scal, xs_bf, b1, h1, n);
  // layer 2
  k_gemm<1><<<dim3((n + 31) / 32, 1), B, 0, stream>>>(h1, W2, xs_bf, as2, ad2,
                                                      a_src2v, a_dst2v, n);
  k_agg2<<<dim3((n + 15) / 16), B, 0, stream>>>(row_ptr, col, a_src2v, a_dst2v,
                                                scal, xs_bf, b2, (float*)d_out, n);
}

// Round 7
// 178.019 us; speedup vs baseline: 2.7120x; 1.1322x over previous
//
#include <hip/hip_runtime.h>
#include <math.h>

#define NEG_SLOPE 0.2f

typedef unsigned int u32;
typedef unsigned short u16;
typedef unsigned long long u64;

typedef __attribute__((ext_vector_type(8))) short short8;   // 8 bf16 = 4 VGPR (MFMA A/B frag)
typedef __attribute__((ext_vector_type(4))) float f32x4;    // MFMA C/D frag

__device__ __forceinline__ float bf2f(u16 h) {
  union { u32 u; float f; } c; c.u = ((u32)h) << 16; return c.f;
}
__device__ __forceinline__ u16 f2bf(float f) {
  union { float f; u32 u; } c; c.f = f;
  return (u16)((c.u + 0x7FFFu + ((c.u >> 16) & 1u)) >> 16);  // RNE, no NaNs expected
}

// ---------------------------------------------------------------- degree + edge-weight sum, packed u64 atomic, 4-way sharded
__global__ void k_deg(const int* __restrict__ dst, const float* __restrict__ ew,
                      u64* __restrict__ packed, u16* __restrict__ rank, int E, int n) {
  int e = blockIdx.x * 256 + threadIdx.x;
  if (e >= E) return;
  u32 fix = __float2uint_rn(ew[e] * 1048576.0f);
  u64 old = atomicAdd(&packed[(size_t)(e & 3) * n + dst[e]], (1ULL << 32) | (u64)fix);
  rank[e] = (u16)(old >> 32);
}

// ---------------------------------------------------------------- hierarchical scan of (deg+1) -> row_ptr
__global__ __launch_bounds__(256) void k_part(const u64* __restrict__ packed,
                                              int* __restrict__ part, int n) {
  int i = blockIdx.x * 256 + threadIdx.x;
  int v = 0;
  if (i < n) {
    u64 pk = packed[i] + packed[(size_t)n + i] + packed[2 * (size_t)n + i] + packed[3 * (size_t)n + i];
    v = (int)(pk >> 32) + 1;
  }
  #pragma unroll
  for (int off = 32; off; off >>= 1) v += __shfl_xor(v, off);
  __shared__ int ws[4];
  if ((threadIdx.x & 63) == 0) ws[threadIdx.x >> 6] = v;
  __syncthreads();
  if (threadIdx.x == 0) part[blockIdx.x] = ws[0] + ws[1] + ws[2] + ws[3];
}

__global__ __launch_bounds__(256) void k_scanpart(int* __restrict__ part, int nb) {
  __shared__ int wsum[4];
  int carry = 0;
  for (int base = 0; base < nb; base += 256) {
    int idx = base + threadIdx.x;
    int orig = (idx < nb) ? part[idx] : 0;
    int v = orig;
    #pragma unroll
    for (int off = 1; off < 64; off <<= 1) {
      int u = __shfl_up(v, off);
      if ((threadIdx.x & 63) >= off) v += u;
    }
    if ((threadIdx.x & 63) == 63) wsum[threadIdx.x >> 6] = v;
    __syncthreads();
    int w = threadIdx.x >> 6;
    int add = 0;
    if (w > 0) add += wsum[0];
    if (w > 1) add += wsum[1];
    if (w > 2) add += wsum[2];
    int excl = v - orig + add + carry;
    if (idx < nb) part[idx] = excl;
    int total = wsum[0] + wsum[1] + wsum[2] + wsum[3];
    __syncthreads();
    carry += total;
  }
}

// phase 3: row_ptr + per-shard base offsets + self-loop entry (slot 0, packed u32)
__global__ __launch_bounds__(256) void k_rowptr(const u64* __restrict__ packed,
                                                const int* __restrict__ part_off,
                                                int* __restrict__ row_ptr,
                                                int4* __restrict__ base4,
                                                u32* __restrict__ col, int n) {
  int i = blockIdx.x * 256 + threadIdx.x;
  u64 q0 = 0, q1 = 0, q2 = 0, q3 = 0;
  if (i < n) {
    q0 = packed[i]; q1 = packed[(size_t)n + i];
    q2 = packed[2 * (size_t)n + i]; q3 = packed[3 * (size_t)n + i];
  }
  int c0 = (int)(q0 >> 32), c1 = (int)(q1 >> 32), c2 = (int)(q2 >> 32), c3 = (int)(q3 >> 32);
  int d = c0 + c1 + c2 + c3;
  u32 sumfix = (u32)q0 + (u32)q1 + (u32)q2 + (u32)q3;
  int orig = (i < n) ? d + 1 : 0;
  int v = orig;
  #pragma unroll
  for (int off = 1; off < 64; off <<= 1) {
    int u = __shfl_up(v, off);
    if ((threadIdx.x & 63) >= off) v += u;
  }
  __shared__ int wsum[4];
  if ((threadIdx.x & 63) == 63) wsum[threadIdx.x >> 6] = v;
  __syncthreads();
  int w = threadIdx.x >> 6;
  int add = 0;
  if (w > 0) add += wsum[0];
  if (w > 1) add += wsum[1];
  if (w > 2) add += wsum[2];
  if (i < n) {
    int excl = v - orig + add + part_off[blockIdx.x];
    row_ptr[i] = excl;
    int b = excl + 1;
    base4[i] = make_int4(b, b + c0, b + c0 + c1, b + c0 + c1 + c2);
    float mean = ((float)sumfix * (1.0f / 1048576.0f)) / (float)(d > 1 ? d : 1);
    u32 wq = (u32)(mean * 65536.0f); if (wq > 65535u) wq = 65535u;
    col[excl] = (u32)i | (wq << 16);                     // self-loop at slot 0
    if (i == n - 1) row_ptr[n] = excl + orig;
  }
}

// ---------------------------------------------------------------- place real edges into CSR slots (no atomics)
__global__ void k_scatter(const int* __restrict__ src, const int* __restrict__ dst,
                          const float* __restrict__ ew, const u16* __restrict__ rank,
                          const int* __restrict__ base4,
                          u32* __restrict__ col, int E) {
  int e = blockIdx.x * 256 + threadIdx.x;
  if (e >= E) return;
  int p = base4[4 * dst[e] + (e & 3)] + rank[e];
  u32 wq = (u32)(ew[e] * 65536.0f); if (wq > 65535u) wq = 65535u;
  col[p] = (u32)src[e] | (wq << 16);
}

// ---------------------------------------------------------------- W -> MFMA B-fragments, hi/lo split planes
// frag f = (cg*4 + t)*2 + p; lane l holds 8 bf16: W[32t + 8*(l>>4) + j][16cg + (l&15)]
template<int H>
__global__ void k_bfrag(const float* __restrict__ W, uint4* __restrict__ bfrag) {
  int tid = blockIdx.x * 256 + threadIdx.x;
  int f = tid >> 6, lane = tid & 63;
  const int NF = H * 4 * 4 * 2;
  if (f >= NF) return;
  int p = f & 1, t = (f >> 1) & 3, cg = f >> 3;
  int colc = 16 * cg + (lane & 15);
  int k0 = 32 * t + 8 * (lane >> 4);
  u16 v[8];
  #pragma unroll
  for (int j = 0; j < 8; j++) {
    float w = W[(size_t)(k0 + j) * (H * 64) + colc];
    u32 bits = __float_as_uint(w);
    if (p == 0) v[j] = (u16)(bits >> 16);                         // truncated hi
    else        v[j] = f2bf(w - __uint_as_float(bits & 0xffff0000u)); // exact residual, RNE
  }
  uint4 o = { (u32)v[0] | ((u32)v[1] << 16), (u32)v[2] | ((u32)v[3] << 16),
              (u32)v[4] | ((u32)v[5] << 16), (u32)v[6] | ((u32)v[7] << 16) };
  bfrag[f * 64 + lane] = o;
}

// ---------------------------------------------------------------- MFMA GEMM (K=128), hi/lo split, bf16 store + fused attn dots
// block = 4 waves x 16 rows; wave covers 16 rows x H*64 cols; LDS-free (A from global, B-frags L2-hot)
template<int H>
__global__ __launch_bounds__(256) void k_gemm_mfma(const float* __restrict__ A,
                                                   const uint4* __restrict__ bfrag,
                                                   u16* __restrict__ xs_bf,
                                                   const float* __restrict__ att_src,
                                                   const float* __restrict__ att_dst,
                                                   float* __restrict__ a_src_out,
                                                   float* __restrict__ a_dst_out,
                                                   int nrows) {
  const int NCG = H * 4;
  int lane = threadIdx.x & 63;
  int wv = threadIdx.x >> 6;
  int lrow = lane & 15, lk = lane >> 4;
  int r0 = blockIdx.x * 64 + wv * 16;
  int arow = r0 + lrow; if (arow > nrows - 1) arow = nrows - 1;
  const float* ap = A + (size_t)arow * 128;

  f32x4 acc[NCG];
  #pragma unroll
  for (int cg = 0; cg < NCG; cg++) acc[cg] = (f32x4){0.f, 0.f, 0.f, 0.f};

  #pragma unroll
  for (int t = 0; t < 4; t++) {
    float4 av0 = *(const float4*)(ap + 32 * t + 8 * lk);
    float4 av1 = *(const float4*)(ap + 32 * t + 8 * lk + 4);
    float af[8] = {av0.x, av0.y, av0.z, av0.w, av1.x, av1.y, av1.z, av1.w};
    short8 ahi, alo;
    #pragma unroll
    for (int j = 0; j < 8; j++) {
      u32 bits = __float_as_uint(af[j]);
      ahi[j] = (short)(bits >> 16);
      alo[j] = (short)f2bf(af[j] - __uint_as_float(bits & 0xffff0000u));
    }
    #pragma unroll
    for (int cg = 0; cg < NCG; cg++) {
      union { uint4 u; short8 s; } bh, bl;
      bh.u = bfrag[((cg * 4 + t) * 2 + 0) * 64 + lane];
      bl.u = bfrag[((cg * 4 + t) * 2 + 1) * 64 + lane];
      acc[cg] = __builtin_amdgcn_mfma_f32_16x16x32_bf16(ahi, bh.s, acc[cg], 0, 0, 0);
      acc[cg] = __builtin_amdgcn_mfma_f32_16x16x32_bf16(ahi, bl.s, acc[cg], 0, 0, 0);
      acc[cg] = __builtin_amdgcn_mfma_f32_16x16x32_bf16(alo, bh.s, acc[cg], 0, 0, 0);
    }
  }

  // epilogue: bf16 xs store + attention partial dots (D layout: col = lane&15, row = 4*(lane>>4)+reg)
  float ps[2][4], pd[2][4];
  #pragma unroll
  for (int h = 0; h < 2; h++)
    #pragma unroll
    for (int r = 0; r < 4; r++) { ps[h][r] = 0.f; pd[h][r] = 0.f; }

  #pragma unroll
  for (int cg = 0; cg < NCG; cg++) {
    int colbase = 16 * cg + lrow;
    float asv = att_src[colbase];
    float adv = att_dst[colbase];
    const int h = (H == 2) ? (cg >> 2) : 0;
    #pragma unroll
    for (int r = 0; r < 4; r++) {
      ps[h][r] += acc[cg][r] * asv;
      pd[h][r] += acc[cg][r] * adv;
      int row = r0 + 4 * lk + r;
      if (row < nrows) xs_bf[(size_t)row * (H * 64) + colbase] = f2bf(acc[cg][r]);
    }
  }
  #pragma unroll
  for (int h = 0; h < H; h++)
    #pragma unroll
    for (int r = 0; r < 4; r++)
      #pragma unroll
      for (int off = 8; off; off >>= 1) {
        ps[h][r] += __shfl_xor(ps[h][r], off);
        pd[h][r] += __shfl_xor(pd[h][r], off);
      }
  if (lrow == 0) {
    #pragma unroll
    for (int r = 0; r < 4; r++) {
      int row = r0 + 4 * lk + r;
      if (row < nrows) {
        #pragma unroll
        for (int h = 0; h < H; h++) {
          a_src_out[row * H + h] = ps[h][r];
          a_dst_out[row * H + h] = pd[h][r];
        }
      }
    }
  }
}

// ---------------------------------------------------------------- edge-attention scalars
__global__ void k_scalars(const float* __restrict__ We1, const float* __restrict__ ae1,
                          const float* __restrict__ We2, const float* __restrict__ ae2,
                          float* __restrict__ out) {
  int t = threadIdx.x;
  if (t == 0) { float s = 0; for (int c = 0; c < 64; c++) s += We1[c] * ae1[c]; out[0] = s; }
  if (t == 1) { float s = 0; for (int c = 0; c < 64; c++) s += We1[64 + c] * ae1[64 + c]; out[1] = s; }
  if (t == 2) { float s = 0; for (int c = 0; c < 64; c++) s += We2[c] * ae2[c]; out[2] = s; }
}

// ---------------------------------------------------------------- layer 1 agg: 16-lane group per node (4 nodes/wave)
__global__ __launch_bounds__(256) void k_agg1(const int* __restrict__ row_ptr,
                                              const u32* __restrict__ col,
                                              const float2* __restrict__ a_src,
                                              const float2* __restrict__ a_dst,
                                              const float* __restrict__ scal,
                                              const u16* __restrict__ xs_bf,
                                              const float* __restrict__ b1,
                                              float* __restrict__ h_out, int n) {
  int wid = (blockIdx.x * 256 + threadIdx.x) >> 4;
  int gl = threadIdx.x & 15;
  if (wid >= n) return;
  int beg = row_ptr[wid], end = row_ptr[wid + 1];
  float2 ad = a_dst[wid];
  float sc0 = scal[0], sc1 = scal[1];
  bool hi = gl >= 8;
  float m0 = -1e30f, m1 = -1e30f, den0 = 0.f, den1 = 0.f;
  float acc[8] = {0.f, 0.f, 0.f, 0.f, 0.f, 0.f, 0.f, 0.f};
  for (int p0 = beg; p0 < end; p0 += 16) {
    int p = p0 + gl;
    bool act = p < end;
    u32 sw = col[act ? p : beg];
    int s = (int)(sw & 0xFFFFu);
    float w = (float)(sw >> 16) * (1.0f / 65536.0f);
    float2 asv = a_src[s];
    float l0 = asv.x + ad.x + w * sc0;
    float l1 = asv.y + ad.y + w * sc1;
    l0 = l0 > 0.f ? l0 : NEG_SLOPE * l0;
    l1 = l1 > 0.f ? l1 : NEG_SLOPE * l1;
    if (!act) { l0 = -1e30f; l1 = -1e30f; }
    float cm0 = l0, cm1 = l1;
    #pragma unroll
    for (int off = 8; off; off >>= 1) {
      cm0 = fmaxf(cm0, __shfl_xor(cm0, off, 16));
      cm1 = fmaxf(cm1, __shfl_xor(cm1, off, 16));
    }
    float nm0 = fmaxf(m0, cm0), nm1 = fmaxf(m1, cm1);
    float e0 = __expf(l0 - nm0), e1 = __expf(l1 - nm1);
    float cs0 = e0, cs1 = e1;
    #pragma unroll
    for (int off = 8; off; off >>= 1) {
      cs0 += __shfl_xor(cs0, off, 16);
      cs1 += __shfl_xor(cs1, off, 16);
    }
    float r0 = __expf(m0 - nm0), r1 = __expf(m1 - nm1);
    den0 = den0 * r0 + cs0;
    den1 = den1 * r1 + cs1;
    float rs = hi ? r1 : r0;
    #pragma unroll
    for (int f = 0; f < 8; f++) acc[f] *= rs;
    m0 = nm0; m1 = nm1;
    int cnt = end - p0; if (cnt > 16) cnt = 16;
    for (int j = 0; j < cnt; j++) {
      float a0 = __shfl(e0, j, 16);
      float a1 = __shfl(e1, j, 16);
      int   sj = __shfl(s, j, 16);
      uint4 q = *(const uint4*)&xs_bf[(size_t)sj * 128 + 8 * gl];
      float al = hi ? a1 : a0;
      acc[0] += al * bf2f((u16)q.x); acc[1] += al * bf2f((u16)(q.x >> 16));
      acc[2] += al * bf2f((u16)q.y); acc[3] += al * bf2f((u16)(q.y >> 16));
      acc[4] += al * bf2f((u16)q.z); acc[5] += al * bf2f((u16)(q.z >> 16));
      acc[6] += al * bf2f((u16)q.w); acc[7] += al * bf2f((u16)(q.w >> 16));
    }
  }
  float inv = 1.f / ((hi ? den1 : den0) + 1e-16f);
  float4 blo = *(const float4*)&b1[8 * gl];
  float4 bhi = *(const float4*)&b1[8 * gl + 4];
  float o[8];
  o[0] = acc[0] * inv + blo.x; o[1] = acc[1] * inv + blo.y;
  o[2] = acc[2] * inv + blo.z; o[3] = acc[3] * inv + blo.w;
  o[4] = acc[4] * inv + bhi.x; o[5] = acc[5] * inv + bhi.y;
  o[6] = acc[6] * inv + bhi.z; o[7] = acc[7] * inv + bhi.w;
  #pragma unroll
  for (int f = 0; f < 8; f++) o[f] = o[f] > 0.f ? o[f] : expm1f(o[f]);   // ELU
  float* dst = &h_out[(size_t)wid * 128 + 8 * gl];
  *(float4*)dst = make_float4(o[0], o[1], o[2], o[3]);
  *(float4*)(dst + 4) = make_float4(o[4], o[5], o[6], o[7]);
}

// ---------------------------------------------------------------- layer 2 agg: 16-lane group per node, 4 features/lane
__global__ __launch_bounds__(256) void k_agg2(const int* __restrict__ row_ptr,
                                              const u32* __restrict__ col,
                                              const float* __restrict__ a_src,
                                              const float* __restrict__ a_dst,
                                              const float* __restrict__ scal,
                                              const u16* __restrict__ xs_bf,
                                              const float* __restrict__ b2,
                                              float* __restrict__ out, int n) {
  int wid = (blockIdx.x * 256 + threadIdx.x) >> 4;
  int gl = threadIdx.x & 15;
  if (wid >= n) return;
  int beg = row_ptr[wid], end = row_ptr[wid + 1];
  float adv = a_dst[wid];
  float sc = scal[2];
  float m = -1e30f, den = 0.f;
  float acc[4] = {0.f, 0.f, 0.f, 0.f};
  for (int p0 = beg; p0 < end; p0 += 16) {
    int p = p0 + gl;
    bool act = p < end;
    u32 sw = col[act ? p : beg];
    int s = (int)(sw & 0xFFFFu);
    float w = (float)(sw >> 16) * (1.0f / 65536.0f);
    float l = a_src[s] + adv + w * sc;
    l = l > 0.f ? l : NEG_SLOPE * l;
    if (!act) l = -1e30f;
    float cm = l;
    #pragma unroll
    for (int off = 8; off; off >>= 1) cm = fmaxf(cm, __shfl_xor(cm, off, 16));
    float nm = fmaxf(m, cm);
    float e = __expf(l - nm);
    float cs = e;
    #pragma unroll
    for (int off = 8; off; off >>= 1) cs += __shfl_xor(cs, off, 16);
    float r = __expf(m - nm);
    den = den * r + cs;
    #pragma unroll
    for (int f = 0; f < 4; f++) acc[f] *= r;
    m = nm;
    int cnt = end - p0; if (cnt > 16) cnt = 16;
    for (int j = 0; j < cnt; j++) {
      float aj = __shfl(e, j, 16);
      int   sj = __shfl(s, j, 16);
      uint2 q = *(const uint2*)&xs_bf[(size_t)sj * 64 + 4 * gl];
      acc[0] += aj * bf2f((u16)q.x); acc[1] += aj * bf2f((u16)(q.x >> 16));
      acc[2] += aj * bf2f((u16)q.y); acc[3] += aj * bf2f((u16)(q.y >> 16));
    }
  }
  float inv = 1.f / (den + 1e-16f);
  float4 b = *(const float4*)&b2[4 * gl];
  *(float4*)&out[(size_t)wid * 64 + 4 * gl] =
      make_float4(acc[0] * inv + b.x, acc[1] * inv + b.y,
                  acc[2] * inv + b.z, acc[3] * inv + b.w);
}

// ================================================================ launch
extern "C" void kernel_launch(void* const* d_in, const int* in_sizes, int n_in,
                              void* d_out, int out_size, void* d_ws, size_t ws_size,
                              hipStream_t stream) {
  const float* x   = (const float*)d_in[0];
  const int*   ei  = (const int*)d_in[1];
  const float* ew  = (const float*)d_in[2];
  const float* W1  = (const float*)d_in[3];
  const float* as1 = (const float*)d_in[4];
  const float* ad1 = (const float*)d_in[5];
  const float* We1 = (const float*)d_in[6];
  const float* ae1 = (const float*)d_in[7];
  const float* b1  = (const float*)d_in[8];
  const float* W2  = (const float*)d_in[9];
  const float* as2 = (const float*)d_in[10];
  const float* ad2 = (const float*)d_in[11];
  const float* We2 = (const float*)d_in[12];
  const float* ae2 = (const float*)d_in[13];
  const float* b2  = (const float*)d_in[14];

  const int n = in_sizes[0] / 128;
  const int E = in_sizes[1] / 2;
  const int Etot = E + n;
  const int nb = (n + 255) / 256;

  char* wsb = (char*)d_ws;
  size_t off = 0;
  auto alloc = [&](size_t bytes) -> void* {
    void* p = wsb + off; off += (bytes + 255) & ~(size_t)255; return p;
  };
  u64*   packed  = (u64*)  alloc((size_t)n * 4 * 8);   // 4 shards: deg<<32 | sum_w_fix20
  u16*   rank    = (u16*)  alloc((size_t)E * 2);
  int*   row_ptr = (int*)  alloc((size_t)(n + 1) * 4);
  int*   base4   = (int*)  alloc((size_t)n * 4 * 4);
  int*   part    = (int*)  alloc((size_t)nb * 4);
  u32*   col     = (u32*)  alloc((size_t)Etot * 4);    // src:16 | wq:16
  uint4* bfrag1  = (uint4*)alloc((size_t)64 * 64 * 16);  // H=2: 64 frags
  uint4* bfrag2  = (uint4*)alloc((size_t)32 * 64 * 16);  // H=1: 32 frags
  u16*   xs_bf   = (u16*)  alloc((size_t)n * 128 * 2); // layer1; reused layer2 (n*64)
  float* h1      = (float*)alloc((size_t)n * 128 * 4);
  float* a_src1v = (float*)alloc((size_t)n * 2 * 4);
  float* a_dst1v = (float*)alloc((size_t)n * 2 * 4);
  float* a_src2v = (float*)alloc((size_t)n * 4);
  float* a_dst2v = (float*)alloc((size_t)n * 4);
  float* scal    = (float*)alloc(64);
  if (off > ws_size) return;

  hipMemsetAsync(packed, 0, (size_t)n * 4 * 8, stream);

  dim3 B(256);
  k_deg<<<dim3((E + 255) / 256), B, 0, stream>>>(ei + E, ew, packed, rank, E, n);
  k_bfrag<2><<<dim3(16), B, 0, stream>>>(W1, bfrag1);
  k_bfrag<1><<<dim3(8), B, 0, stream>>>(W2, bfrag2);
  k_scalars<<<1, 64, 0, stream>>>(We1, ae1, We2, ae2, scal);
  k_part<<<dim3(nb), B, 0, stream>>>(packed, part, n);
  k_scanpart<<<1, B, 0, stream>>>(part, nb);
  k_rowptr<<<dim3(nb), B, 0, stream>>>(packed, part, row_ptr, (int4*)base4, col, n);
  k_scatter<<<dim3((E + 255) / 256), B, 0, stream>>>(ei, ei + E, ew, rank, base4, col, E);
  // layer 1
  k_gemm_mfma<2><<<dim3((n + 63) / 64), B, 0, stream>>>(x, bfrag1, xs_bf, as1, ad1,
                                                        a_src1v, a_dst1v, n);
  k_agg1<<<dim3((n + 15) / 16), B, 0, stream>>>(row_ptr, col,
                                                (const float2*)a_src1v,
                                                (const float2*)a_dst1v,
                                                scal, xs_bf, b1, h1, n);
  // layer 2
  k_gemm_mfma<1><<<dim3((n + 63) / 64), B, 0, stream>>>(h1, bfrag2, xs_bf, as2, ad2,
                                                        a_src2v, a_dst2v, n);
  k_agg2<<<dim3((n + 15) / 16), B, 0, stream>>>(row_ptr, col, a_src2v, a_dst2v,
                                                scal, xs_bf, b2, (float*)d_out, n);
}